// Round 3
// baseline (219.496 us; speedup 1.0000x reference)
//
#include <hip/hip_runtime.h>
#include <hip/hip_bf16.h>

using f16 = _Float16;
typedef _Float16 f16x8 __attribute__((ext_vector_type(8)));
typedef _Float16 f16x4 __attribute__((ext_vector_type(4)));
typedef float f32x4 __attribute__((ext_vector_type(4)));

#define AS1 __attribute__((address_space(1)))
#define AS3 __attribute__((address_space(3)))

// Problem constants
constexpr int Bc = 4, Qc = 1024, Dc = 1024, Nh = 16, DHc = 64;
constexpr int BQ = Bc * Qc;      // 4096 rows of w
constexpr int NHEAD = Bc * Nh;   // 64 (b,n) heads
constexpr float ATT_SCALE = 0.125f;

// ---------------- f32 -> f16, 8 elems/thread ----------------
__global__ void k_f2h(const float* __restrict__ src, f16* __restrict__ dst) {
    long i8 = ((long)blockIdx.x * blockDim.x + threadIdx.x) * 8;
    float4 a = *(const float4*)&src[i8];
    float4 b = *(const float4*)&src[i8 + 4];
    f16x8 o = { (f16)a.x, (f16)a.y, (f16)a.z, (f16)a.w,
                (f16)b.x, (f16)b.y, (f16)b.z, (f16)b.w };
    *(f16x8*)&dst[i8] = o;
}

// ---------------- merged 4-way weight transpose: src[z][R][C] -> dst[z][C][R] f16 ----------------
struct Ptr4 { const float* p[4]; };
__global__ void k_transpose4(Ptr4 srcs, f16* __restrict__ dst) {
    __shared__ f16 tile[32][33];
    const float* src = srcs.p[blockIdx.z];
    f16* d = dst + (long)blockIdx.z * Dc * Dc;
    int c0 = blockIdx.x * 32, r0 = blockIdx.y * 32;
#pragma unroll
    for (int dy = 0; dy < 32; dy += 8) {
        int r = r0 + threadIdx.y + dy, c = c0 + threadIdx.x;
        tile[threadIdx.y + dy][threadIdx.x] = (f16)src[(long)r * Dc + c];
    }
    __syncthreads();
#pragma unroll
    for (int dy = 0; dy < 32; dy += 8) {
        int c = c0 + threadIdx.y + dy, r = r0 + threadIdx.x;
        d[(long)c * Dc + r] = tile[threadIdx.x][threadIdx.y + dy];
    }
}

// ---------------- Ke[h][j][0:64] = r_emb[j+1][n][:] (0 at j=1023) ----------------
__global__ void k_fill_remb(const float* __restrict__ remb, f16* __restrict__ Ke) {
    long gid = (long)blockIdx.x * blockDim.x + threadIdx.x;  // 64*1024*8
    int d8 = (int)(gid & 7) * 8;
    int j = (int)((gid >> 3) & 1023);
    int h = (int)(gid >> 13);
    int n = h & 15;
    f16x8 kv;
    if (j < 1023) {
        const float* rp = &remb[((long)(j + 1) * 16 + n) * 64 + d8];
        float4 r0 = *(const float4*)rp, r1 = *(const float4*)(rp + 4);
        kv[0] = (f16)r0.x; kv[1] = (f16)r0.y; kv[2] = (f16)r0.z; kv[3] = (f16)r0.w;
        kv[4] = (f16)r1.x; kv[5] = (f16)r1.y; kv[6] = (f16)r1.z; kv[7] = (f16)r1.w;
    } else {
        kv = f16x8{};
    }
    *(f16x8*)&Ke[(((long)h << 10) + j) * 64 + d8] = kv;
}

// ---------------- NT GEMM, global_load_lds staging, fused epilogues ----------------
// EPI: 0 = f16 row-major; 5 = QKV: seg0/1 natural row-major to qtp/ktp, seg2 vT scatter.
template <int BM, int BN, int BK, int WROWS, int WCOLS, int EPI>
__global__ __launch_bounds__(256) void k_gemm_nt(
    const f16* __restrict__ A, const f16* __restrict__ Bt, void* __restrict__ Cv,
    f16* __restrict__ qtp, f16* __restrict__ ktp, f16* __restrict__ vtp,
    int lda, int ldb, int ldc, int K)
{
    constexpr int TM = BM / (WROWS * 16);
    constexpr int TN = BN / (WCOLS * 16);
    __shared__ __align__(16) f16 sA[BM * BK];
    __shared__ __align__(16) f16 sB[BN * BK];

    const int tid = threadIdx.x;
    const int lane = tid & 63, wave = tid >> 6;
    const int wm = wave / WCOLS, wn = wave % WCOLS;
    const int m0 = blockIdx.y * BM, n0 = blockIdx.x * BN;

    f32x4 acc[TM][TN] = {};

    const int lrow = lane & 15;
    const int kq = (lane >> 4) * 8;
    const int srow = lane >> 2;            // 16 rows per 1KB chunk
    const int scol = (lane & 3) * 8;       // 4 lanes x 8 f16 per 64B row

    for (int k0 = 0; k0 < K; k0 += BK) {
        __syncthreads();
        constexpr int CHA = BM * BK / 512;   // 1KB chunks
#pragma unroll
        for (int ch = 0; ch < CHA / 4; ++ch) {
            int cc = ch * 4 + wave;
            __builtin_amdgcn_global_load_lds(
                (const AS1 void*)(const void*)&A[(long)(m0 + cc * 16 + srow) * lda + k0 + scol],
                (AS3 void*)(void*)&sA[cc * 512], 16, 0, 0);
        }
        constexpr int CHB = BN * BK / 512;
#pragma unroll
        for (int ch = 0; ch < CHB / 4; ++ch) {
            int cc = ch * 4 + wave;
            __builtin_amdgcn_global_load_lds(
                (const AS1 void*)(const void*)&Bt[(long)(n0 + cc * 16 + srow) * ldb + k0 + scol],
                (AS3 void*)(void*)&sB[cc * 512], 16, 0, 0);
        }
        __syncthreads();

        f16x8 af[TM], bfr[TN];
#pragma unroll
        for (int mi = 0; mi < TM; ++mi)
            af[mi] = *(const f16x8*)&sA[(wm * TM * 16 + mi * 16 + lrow) * BK + kq];
#pragma unroll
        for (int ni = 0; ni < TN; ++ni)
            bfr[ni] = *(const f16x8*)&sB[(wn * TN * 16 + ni * 16 + lrow) * BK + kq];
#pragma unroll
        for (int mi = 0; mi < TM; ++mi)
#pragma unroll
            for (int ni = 0; ni < TN; ++ni)
                acc[mi][ni] = __builtin_amdgcn_mfma_f32_16x16x32_f16(af[mi], bfr[ni], acc[mi][ni], 0, 0, 0);
    }

    const int crow = (lane >> 4) * 4;
    const int ccol = lane & 15;
#pragma unroll
    for (int mi = 0; mi < TM; ++mi)
#pragma unroll
        for (int ni = 0; ni < TN; ++ni)
#pragma unroll
            for (int r = 0; r < 4; ++r) {
                int gm = m0 + wm * TM * 16 + mi * 16 + crow + r;
                int gn = n0 + wn * TN * 16 + ni * 16 + ccol;
                float val = acc[mi][ni][r];
                if constexpr (EPI == 0) {
                    ((f16*)Cv)[(long)gm * ldc + gn] = (f16)val;
                } else {
                    int seg = n0 >> 10;       // block-uniform (BN=128 | 1024)
                    int col = gn & 1023;
                    if (seg == 0) {
                        qtp[(long)gm * 1024 + col] = (f16)val;
                    } else if (seg == 1) {
                        ktp[(long)gm * 1024 + col] = (f16)val;
                    } else {
                        int b = gm >> 10, i = gm & 1023;
                        vtp[(((long)(b << 10) + col) << 10) + i] = (f16)val;
                    }
                }
            }
}

// ---------------- fused flash attention v9: v8 + sV XOR-swizzle (T2 for b64 reads).
// Conflict attribution: v6/v8 SQ_LDS_BANK_CONFLICT were exactly 2^22/2^23 =
// 8 cycles x (sV b64 read count) -> sV was 100% of conflicts; sK b128 is clean.
// New sV layout: 256B rows (LDV=128, no pad), 8B-chunk index j8 swizzled
// j8' = (j8&16) | ((j8&15) ^ (d&15)). Read quarter (fixed quad) has d&15=lrow
// distinct -> start banks 2*(j8&15^lrow) = all 16 even pairs, conflict-free.
// Write side applies the same involution: XOR bit0 flip = swap 8B halves of
// the 16B chunk -> still a single uint4 store (halves swapped when d odd).
// Tripwires: WRITE_SIZE == 8192 KB; FETCH ~16.7MB; absmax == 0.03125;
// SQ_LDS_BANK_CONFLICT must collapse (<1M) else attribution wrong -> revert.
__global__ __launch_bounds__(512, 4) void k_flash(
    const f16* __restrict__ qh, const f16* __restrict__ kh,
    const f16* __restrict__ Ke, const f16* __restrict__ vT,
    const float* __restrict__ rwb, const float* __restrict__ r_bias,
    f16* __restrict__ avp)
{
    constexpr int LDL = 136;   // sK row stride (f16)
    constexpr int LDV = 128;   // sV row stride (f16), swizzled
    __shared__ __align__(16) f16 sK[128 * LDL];   // cols 0..63 = k, 64..127 = remb
    __shared__ __align__(16) f16 sV[64 * LDV];
    __shared__ float sRB[128];

    const int tid = threadIdx.x, lane = tid & 63, wave = tid >> 6;  // wave 0..7
    const int bid = blockIdx.x;
    const int h = (((bid >> 3) & 7) << 3) | (bid & 7);
    const int i0 = (bid >> 6) * 128;
    const int b = h >> 4, n = h & 15;

    const f16* Vh = vT + (long)h * DHc * Qc;

    const int lrow = lane & 15;            // q (B-frag n) / row index
    const int quad = lane >> 4;

    // r_w_bias fragments (f32 -> f16), pre-scaled by ATT_SCALE
    f16x8 rw0, rw1;
#pragma unroll
    for (int e = 0; e < 8; ++e) {
        rw0[e] = (f16)(rwb[n * 64 + quad * 8 + e] * ATT_SCALE);
        rw1[e] = (f16)(rwb[n * 64 + 32 + quad * 8 + e] * ATT_SCALE);
    }

    // Q fragments (B-operand of S^T): wave owns q rows [i0+wave*16, +16).
    // q loaded once, scaled by ATT_SCALE (exact f16 pow2 mul).
    const f16 qsc = (f16)0.125f;
    f16x8 aq[4];
    {
        long rix = (long)(b * Qc + i0 + wave * 16 + lrow) * 1024 + n * 64;
        f16x8 q0 = *(const f16x8*)&qh[rix + quad * 8] * qsc;
        f16x8 q1 = *(const f16x8*)&qh[rix + 32 + quad * 8] * qsc;
        aq[0] = q0 + rw0;   // k-dim [0,32):  (q + r_w_bias) * scale
        aq[1] = q1 + rw1;   // k-dim [32,64)
        aq[2] = q0;         // k-dim [64,96):  q * scale (dot r_emb half)
        aq[3] = q1;         // k-dim [96,128)
    }

    float m_i = -1e30f, l_i = 0.0f;
    f32x4 o_acc[4] = {};   // D[m=q][n=d]: row q=quad*4+reg, col d=lane&15

    for (int j0 = 0; j0 < Qc; j0 += 128) {
        __syncthreads();   // prev iter's sK/sV/sRB reads complete
        for (int idx = tid; idx < 1024; idx += 512) {
            int r = idx >> 3, c = (idx & 7) * 8;
            *(uint4*)&sK[r * LDL + c] =
                *(const uint4*)&kh[(long)(b * Qc + j0 + r) * 1024 + n * 64 + c];
            *(uint4*)&sK[r * LDL + 64 + c] =
                *(const uint4*)&Ke[((long)h * Qc + j0 + r) * 64 + c];
        }
        for (int idx = tid; idx < 64 * 16; idx += 512) {
            int r = idx >> 4, c16 = idx & 15;
            uint4 v = *(const uint4*)&Vh[(long)r * Qc + j0 + c16 * 8];
            // swizzled 8B-chunk index for the first half (t=0): j8 = 2*c16
            int swz0 = ((2 * c16) & 16) | (((2 * c16) & 15) ^ (r & 15));
            int pair = swz0 & ~1;            // 16B-aligned 8B-chunk pair
            uint4 wv;
            if (r & 1) { wv.x = v.z; wv.y = v.w; wv.z = v.x; wv.w = v.y; }
            else        wv = v;
            *(uint4*)&sV[r * LDV + pair * 4] = wv;   // pair*4 f16 = pair*8 bytes
        }
        if (tid < 128) {
            int j = j0 + tid;
            sRB[tid] = (j < Qc - 1) ? r_bias[(j + 1) * Nh + n] * ATT_SCALE : 0.0f;
        }
        __syncthreads();

        // S^T: D[m=j][n=q], 128 j x 16 q per wave
        f32x4 s_acc[8] = {};
#pragma unroll
        for (int kc = 0; kc < 4; ++kc)
#pragma unroll
            for (int ni = 0; ni < 8; ++ni) {
                f16x8 bk = *(const f16x8*)&sK[(ni * 16 + lrow) * LDL + kc * 32 + quad * 8];
                s_acc[ni] = __builtin_amdgcn_mfma_f32_16x16x32_f16(bk, aq[kc], s_acc[ni], 0, 0, 0);
            }

        // online softmax per q (= lane&15); j spread over regs (x4) and quads (x4)
        f16x4 pf[8];
        float mx = -1e30f;
#pragma unroll
        for (int ni = 0; ni < 8; ++ni) {
            f32x4 rb4 = *(const f32x4*)&sRB[ni * 16 + quad * 4];
#pragma unroll
            for (int r = 0; r < 4; ++r) {
                float v = s_acc[ni][r] + rb4[r];   // scale pre-folded
                s_acc[ni][r] = v;
                mx = fmaxf(mx, v);
            }
        }
        mx = fmaxf(mx, __shfl_xor(mx, 16));
        mx = fmaxf(mx, __shfl_xor(mx, 32));
        float mn = fmaxf(m_i, mx);
        float alpha = __expf(m_i - mn);
        float sm = 0.0f;
#pragma unroll
        for (int ni = 0; ni < 8; ++ni) {
            float e0 = __expf(s_acc[ni][0] - mn);
            float e1 = __expf(s_acc[ni][1] - mn);
            float e2 = __expf(s_acc[ni][2] - mn);
            float e3 = __expf(s_acc[ni][3] - mn);
            sm += (e0 + e1) + (e2 + e3);
            f16x4 pvv; pvv[0] = (f16)e0; pvv[1] = (f16)e1; pvv[2] = (f16)e2; pvv[3] = (f16)e3;
            pf[ni] = pvv;
        }
        sm += __shfl_xor(sm, 16);
        sm += __shfl_xor(sm, 32);
        l_i = l_i * alpha + sm;
        m_i = mn;

        // rescale o_acc: broadcast alpha from lane (quad*4+r) of the q-group
#pragma unroll
        for (int r = 0; r < 4; ++r) {
            float al = __shfl(alpha, quad * 4 + r);
#pragma unroll
            for (int dt = 0; dt < 4; ++dt) o_acc[dt][r] *= al;
        }

        // PV: D[m=q][n=d] += P[q][j] * V[j][d], K=16 chunks, P from registers.
        // sV read with the same swizzle: j8 = 4*nj + quad, row d has d&15 = lrow.
#pragma unroll
        for (int nj = 0; nj < 8; ++nj) {
            int j8 = 4 * nj + quad;
            int offv = ((j8 & 16) | ((j8 & 15) ^ lrow)) * 4;   // f16 units
#pragma unroll
            for (int dt = 0; dt < 4; ++dt) {
                f16x4 bv = *(const f16x4*)&sV[(dt * 16 + lrow) * LDV + offv];
                o_acc[dt] = __builtin_amdgcn_mfma_f32_16x16x16f16(pf[nj], bv, o_acc[dt], 0, 0, 0);
            }
        }
    }

    // epilogue: avp[b][i][n*64+d] = O / l  (row q=quad*4+r, col d=lane&15)
    {
        float linv = 1.0f / l_i;
#pragma unroll
        for (int r = 0; r < 4; ++r) {
            float li = __shfl(linv, quad * 4 + r);
            int i = i0 + wave * 16 + quad * 4 + r;
#pragma unroll
            for (int dt = 0; dt < 4; ++dt) {
                int d = dt * 16 + lrow;
                avp[((long)(b * Qc + i) << 10) + n * 64 + d] = (f16)(o_acc[dt][r] * li);
            }
        }
    }
}

// ---------------- residual + LayerNorm (w f32, ao f16; f32 output) ----------------
__global__ __launch_bounds__(256) void k_res_ln(const float* __restrict__ w, const f16* __restrict__ ao,
                                                const float* __restrict__ gamma, const float* __restrict__ beta,
                                                float* __restrict__ out) {
    const long base = (long)blockIdx.x * 1024;
    const int tid = threadIdx.x;
    float4 wv = *(const float4*)&w[base + tid * 4];
    f16x4 av = *(const f16x4*)&ao[base + tid * 4];
    float x[4] = { wv.x + (float)av[0], wv.y + (float)av[1],
                   wv.z + (float)av[2], wv.w + (float)av[3] };
    float s = x[0] + x[1] + x[2] + x[3];
    float s2 = x[0] * x[0] + x[1] * x[1] + x[2] * x[2] + x[3] * x[3];
#pragma unroll
    for (int off = 32; off; off >>= 1) { s += __shfl_down(s, off); s2 += __shfl_down(s2, off); }
    __shared__ float rs[4], rs2[4];
    if ((tid & 63) == 0) { rs[tid >> 6] = s; rs2[tid >> 6] = s2; }
    __syncthreads();
    s = rs[0] + rs[1] + rs[2] + rs[3];
    s2 = rs2[0] + rs2[1] + rs2[2] + rs2[3];
    float mu = s * (1.0f / 1024.0f);
    float var = s2 * (1.0f / 1024.0f) - mu * mu;
    float inv = rsqrtf(var + 1e-5f);
    float4 gv = *(const float4*)&gamma[tid * 4];
    float4 bv = *(const float4*)&beta[tid * 4];
    float4 o;
    o.x = (x[0] - mu) * inv * gv.x + bv.x;
    o.y = (x[1] - mu) * inv * gv.y + bv.y;
    o.z = (x[2] - mu) * inv * gv.z + bv.z;
    o.w = (x[3] - mu) * inv * gv.w + bv.w;
    *(float4*)&out[base + tid * 4] = o;
}

extern "C" void kernel_launch(void* const* d_in, const int* in_sizes, int n_in,
                              void* d_out, int out_size, void* d_ws, size_t ws_size,
                              hipStream_t stream) {
    const float* w_in   = (const float*)d_in[0];
    const float* r_emb  = (const float*)d_in[1];
    const float* r_wb   = (const float*)d_in[2];
    const float* r_bias = (const float*)d_in[3];
    const float* Wq     = (const float*)d_in[4];
    const float* Wk     = (const float*)d_in[5];
    const float* Wv     = (const float*)d_in[6];
    const float* Wo     = (const float*)d_in[7];
    const float* ln_g   = (const float*)d_in[8];
    const float* ln_b   = (const float*)d_in[9];
    float* out = (float*)d_out;

    // workspace carve-out (48MB fixed + aliases)
    char* p = (char*)d_ws;
    auto alloc = [&](size_t bytes) { char* r = p; p += (bytes + 255) & ~(size_t)255; return r; };
    f16* wh = (f16*)alloc((size_t)BQ * Dc * 2);          // 8 MB
    f16* WT = (f16*)alloc((size_t)4 * Dc * Dc * 2);      // 8 MB: WqT,WkT,WvT,WoT (contiguous)
    f16* qh = (f16*)alloc((size_t)BQ * Dc * 2);          // 8 MB [b*Q+i][n*64+d]
    f16* kh = (f16*)alloc((size_t)BQ * Dc * 2);          // 8 MB [b*Q+j][n*64+d]
    f16* Ke = (f16*)alloc((size_t)NHEAD * Qc * DHc * 2); // 8 MB [h][j][64] rel-shifted r_emb
    f16* vT = (f16*)alloc((size_t)BQ * Dc * 2);          // 8 MB [b][dcol][j]
    f16* WoT = WT + (size_t)3 * Dc * Dc;
    // aliases (liveness-checked): wh dead after QKV GEMM; Ke dead after flash
    f16* avp = wh;                 // [b][i][1024] f16
    f16* ao  = Ke;                 // 8 MB f16

    // 1. f32->f16 of w (8/thread)
    k_f2h<<<(BQ * Dc) / (256 * 8), 256, 0, stream>>>(w_in, wh);

    // 2. transpose 4 weights in one dispatch (f32 -> f16)
    Ptr4 srcs{{Wq, Wk, Wv, Wo}};
    k_transpose4<<<dim3(32, 32, 4), dim3(32, 8), 0, stream>>>(srcs, WT);

    // 3. rel-shifted r_emb -> Ke (independent of GEMMs)
    k_fill_remb<<<(NHEAD * Qc * 8) / 256, 256, 0, stream>>>(r_emb, Ke);

    // 4. fused QKV projection: N=3072; seg0/1 natural row-major, seg2 vT scatter
    k_gemm_nt<128, 128, 32, 2, 2, 5><<<dim3(3 * Dc / 128, BQ / 128), 256, 0, stream>>>(
        wh, WT, nullptr, qh, kh, vT, Dc, Dc, 0, Dc);

    // 5. fused attention (XCD-swizzled 1D grid 512, 8-wave blocks)
    k_flash<<<512, 512, 0, stream>>>(qh, kh, Ke, vT, r_wb, r_bias, avp);

    // 6. attn_out = avp @ Wo^T (64x128 tile -> 512 blocks; f16 out into aliased ao)
    k_gemm_nt<64, 128, 32, 2, 2, 0><<<dim3(Dc / 128, BQ / 64), 256, 0, stream>>>(
        avp, WoT, ao, nullptr, nullptr, nullptr, Dc, Dc, Dc, Dc);

    // 7. out = LayerNorm(w + attn_out), fp32 output
    k_res_ln<<<BQ, 256, 0, stream>>>(w_in, ao, ln_g, ln_b, out);
}

// Round 4
// 216.615 us; speedup vs baseline: 1.0133x; 1.0133x over previous
//
#include <hip/hip_runtime.h>
#include <hip/hip_bf16.h>

using f16 = _Float16;
typedef _Float16 f16x8 __attribute__((ext_vector_type(8)));
typedef _Float16 f16x4 __attribute__((ext_vector_type(4)));
typedef float f32x4 __attribute__((ext_vector_type(4)));

#define AS1 __attribute__((address_space(1)))
#define AS3 __attribute__((address_space(3)))

// Problem constants
constexpr int Bc = 4, Qc = 1024, Dc = 1024, Nh = 16, DHc = 64;
constexpr int BQ = Bc * Qc;      // 4096 rows of w
constexpr int NHEAD = Bc * Nh;   // 64 (b,n) heads
constexpr float ATT_SCALE = 0.125f;

// ---------------- f32 -> f16, 8 elems/thread ----------------
__global__ void k_f2h(const float* __restrict__ src, f16* __restrict__ dst) {
    long i8 = ((long)blockIdx.x * blockDim.x + threadIdx.x) * 8;
    float4 a = *(const float4*)&src[i8];
    float4 b = *(const float4*)&src[i8 + 4];
    f16x8 o = { (f16)a.x, (f16)a.y, (f16)a.z, (f16)a.w,
                (f16)b.x, (f16)b.y, (f16)b.z, (f16)b.w };
    *(f16x8*)&dst[i8] = o;
}

// ---------------- merged 4-way weight transpose: src[z][R][C] -> dst[z][C][R] f16 ----------------
struct Ptr4 { const float* p[4]; };
__global__ void k_transpose4(Ptr4 srcs, f16* __restrict__ dst) {
    __shared__ f16 tile[32][33];
    const float* src = srcs.p[blockIdx.z];
    f16* d = dst + (long)blockIdx.z * Dc * Dc;
    int c0 = blockIdx.x * 32, r0 = blockIdx.y * 32;
#pragma unroll
    for (int dy = 0; dy < 32; dy += 8) {
        int r = r0 + threadIdx.y + dy, c = c0 + threadIdx.x;
        tile[threadIdx.y + dy][threadIdx.x] = (f16)src[(long)r * Dc + c];
    }
    __syncthreads();
#pragma unroll
    for (int dy = 0; dy < 32; dy += 8) {
        int c = c0 + threadIdx.y + dy, r = r0 + threadIdx.x;
        d[(long)c * Dc + r] = tile[threadIdx.x][threadIdx.y + dy];
    }
}

// ---------------- Ke[h][j][0:64] = r_emb[j+1][n][:] (0 at j=1023) ----------------
__global__ void k_fill_remb(const float* __restrict__ remb, f16* __restrict__ Ke) {
    long gid = (long)blockIdx.x * blockDim.x + threadIdx.x;  // 64*1024*8
    int d8 = (int)(gid & 7) * 8;
    int j = (int)((gid >> 3) & 1023);
    int h = (int)(gid >> 13);
    int n = h & 15;
    f16x8 kv;
    if (j < 1023) {
        const float* rp = &remb[((long)(j + 1) * 16 + n) * 64 + d8];
        float4 r0 = *(const float4*)rp, r1 = *(const float4*)(rp + 4);
        kv[0] = (f16)r0.x; kv[1] = (f16)r0.y; kv[2] = (f16)r0.z; kv[3] = (f16)r0.w;
        kv[4] = (f16)r1.x; kv[5] = (f16)r1.y; kv[6] = (f16)r1.z; kv[7] = (f16)r1.w;
    } else {
        kv = f16x8{};
    }
    *(f16x8*)&Ke[(((long)h << 10) + j) * 64 + d8] = kv;
}

// ---------------- NT GEMM, global_load_lds staging, fused epilogues ----------------
// EPI: 0 = f16 row-major; 5 = QKV: seg0/1 natural row-major to qtp/ktp, seg2 vT scatter.
template <int BM, int BN, int BK, int WROWS, int WCOLS, int EPI>
__global__ __launch_bounds__(256) void k_gemm_nt(
    const f16* __restrict__ A, const f16* __restrict__ Bt, void* __restrict__ Cv,
    f16* __restrict__ qtp, f16* __restrict__ ktp, f16* __restrict__ vtp,
    int lda, int ldb, int ldc, int K)
{
    constexpr int TM = BM / (WROWS * 16);
    constexpr int TN = BN / (WCOLS * 16);
    __shared__ __align__(16) f16 sA[BM * BK];
    __shared__ __align__(16) f16 sB[BN * BK];

    const int tid = threadIdx.x;
    const int lane = tid & 63, wave = tid >> 6;
    const int wm = wave / WCOLS, wn = wave % WCOLS;
    const int m0 = blockIdx.y * BM, n0 = blockIdx.x * BN;

    f32x4 acc[TM][TN] = {};

    const int lrow = lane & 15;
    const int kq = (lane >> 4) * 8;
    const int srow = lane >> 2;            // 16 rows per 1KB chunk
    const int scol = (lane & 3) * 8;       // 4 lanes x 8 f16 per 64B row

    for (int k0 = 0; k0 < K; k0 += BK) {
        __syncthreads();
        constexpr int CHA = BM * BK / 512;   // 1KB chunks
#pragma unroll
        for (int ch = 0; ch < CHA / 4; ++ch) {
            int cc = ch * 4 + wave;
            __builtin_amdgcn_global_load_lds(
                (const AS1 void*)(const void*)&A[(long)(m0 + cc * 16 + srow) * lda + k0 + scol],
                (AS3 void*)(void*)&sA[cc * 512], 16, 0, 0);
        }
        constexpr int CHB = BN * BK / 512;
#pragma unroll
        for (int ch = 0; ch < CHB / 4; ++ch) {
            int cc = ch * 4 + wave;
            __builtin_amdgcn_global_load_lds(
                (const AS1 void*)(const void*)&Bt[(long)(n0 + cc * 16 + srow) * ldb + k0 + scol],
                (AS3 void*)(void*)&sB[cc * 512], 16, 0, 0);
        }
        __syncthreads();

        f16x8 af[TM], bfr[TN];
#pragma unroll
        for (int mi = 0; mi < TM; ++mi)
            af[mi] = *(const f16x8*)&sA[(wm * TM * 16 + mi * 16 + lrow) * BK + kq];
#pragma unroll
        for (int ni = 0; ni < TN; ++ni)
            bfr[ni] = *(const f16x8*)&sB[(wn * TN * 16 + ni * 16 + lrow) * BK + kq];
#pragma unroll
        for (int mi = 0; mi < TM; ++mi)
#pragma unroll
            for (int ni = 0; ni < TN; ++ni)
                acc[mi][ni] = __builtin_amdgcn_mfma_f32_16x16x32_f16(af[mi], bfr[ni], acc[mi][ni], 0, 0, 0);
    }

    const int crow = (lane >> 4) * 4;
    const int ccol = lane & 15;
#pragma unroll
    for (int mi = 0; mi < TM; ++mi)
#pragma unroll
        for (int ni = 0; ni < TN; ++ni)
#pragma unroll
            for (int r = 0; r < 4; ++r) {
                int gm = m0 + wm * TM * 16 + mi * 16 + crow + r;
                int gn = n0 + wn * TN * 16 + ni * 16 + ccol;
                float val = acc[mi][ni][r];
                if constexpr (EPI == 0) {
                    ((f16*)Cv)[(long)gm * ldc + gn] = (f16)val;
                } else {
                    int seg = n0 >> 10;       // block-uniform (BN=128 | 1024)
                    int col = gn & 1023;
                    if (seg == 0) {
                        qtp[(long)gm * 1024 + col] = (f16)val;
                    } else if (seg == 1) {
                        ktp[(long)gm * 1024 + col] = (f16)val;
                    } else {
                        int b = gm >> 10, i = gm & 1023;
                        vtp[(((long)(b << 10) + col) << 10) + i] = (f16)val;
                    }
                }
            }
}

// ---------------- fused flash attention v10: async double-buffered staging.
// Lesson from v9: removing 4.2M bank-conflict cycles changed dur by 0 -> LDS
// conflicts are NOT the critical path; the serial stage->barrier->compute
// structure is. Fix: KVBLK=64, three linear [64][64] tiles (sKa=kh, sKe=Ke,
// sVa=vT) double-buffered (48.5 KB, still 2 blocks/CU). Staging = exactly 3
// global_load_lds per thread (spill-proof, no VGPR round trip), issued at the
// TOP of each iter into the spare buffer; ONE __syncthreads per iter whose
// vmcnt(0) drain lands after compute has hidden the L2 latency (T3 depth-1).
// Rule #21: linear LDS dest + inverse-swizzled GLOBAL source (16B chunk
// ^ (row&7)) + same XOR on reads -> sK reads keep 8-bank spread.
// r_bias prefetched into a scalar reg (no arrays -> no spill).
// Tripwires: WRITE_SIZE == 8192 KB, VGPR <= 128 (no spill); FETCH ~16.7MB.
__global__ __launch_bounds__(512, 4) void k_flash(
    const f16* __restrict__ qh, const f16* __restrict__ kh,
    const f16* __restrict__ Ke, const f16* __restrict__ vT,
    const float* __restrict__ rwb, const float* __restrict__ r_bias,
    f16* __restrict__ avp)
{
    __shared__ __align__(16) f16 sKa[2][64 * 64];   // kh tile: [j-local][d]
    __shared__ __align__(16) f16 sKe[2][64 * 64];   // Ke tile: [j-local][d]
    __shared__ __align__(16) f16 sVa[2][64 * 64];   // vT tile: [d][j-local]
    __shared__ float sRB[2][64];

    const int tid = threadIdx.x, lane = tid & 63, wave = tid >> 6;  // wave 0..7
    const int bid = blockIdx.x;
    const int h = (((bid >> 3) & 7) << 3) | (bid & 7);
    const int i0 = (bid >> 6) * 128;
    const int b = h >> 4, n = h & 15;

    const int lrow = lane & 15;            // q (B-frag n) / row index
    const int quad = lane >> 4;
    const int lr3 = lane >> 3;             // staging: row within wave's 8-row slice
    const int swc = (lane & 7) ^ (lr3 & 7);  // inverse-swizzled source 16B chunk

    // wave-slice per-lane source pointers (tile row = 8*wave + lr3)
    const f16* srcK = kh + ((long)(b * Qc) + 8 * wave + lr3) * 1024 + n * 64 + swc * 8;
    const f16* srcE = Ke + ((long)h * Qc + 8 * wave + lr3) * 64 + swc * 8;
    const f16* srcV = vT + (long)h * DHc * Qc + (long)(8 * wave + lr3) * Qc + swc * 8;

    // r_w_bias fragments (f32 -> f16), pre-scaled by ATT_SCALE
    f16x8 rw0, rw1;
#pragma unroll
    for (int e = 0; e < 8; ++e) {
        rw0[e] = (f16)(rwb[n * 64 + quad * 8 + e] * ATT_SCALE);
        rw1[e] = (f16)(rwb[n * 64 + 32 + quad * 8 + e] * ATT_SCALE);
    }

    // Q fragments (B-operand of S^T): wave owns q rows [i0+wave*16, +16).
    const f16 qsc = (f16)0.125f;
    f16x8 aq[4];
    {
        long rix = (long)(b * Qc + i0 + wave * 16 + lrow) * 1024 + n * 64;
        f16x8 q0 = *(const f16x8*)&qh[rix + quad * 8] * qsc;
        f16x8 q1 = *(const f16x8*)&qh[rix + 32 + quad * 8] * qsc;
        aq[0] = q0 + rw0;   // k-dim [0,32):  (q + r_w_bias) * scale, dot kh
        aq[1] = q1 + rw1;   // k-dim [32,64)
        aq[2] = q0;         // k-dim [64,96):  q * scale, dot Ke
        aq[3] = q1;         // k-dim [96,128)
    }

    float m_i = -1e30f, l_i = 0.0f;
    f32x4 o_acc[4] = {};   // D[m=q][n=d]: row q=quad*4+reg, col d=lane&15

    // prologue: stage tile 0 (async) + rb0
    {
        float rbv = 0.0f;
        if (tid < 64) rbv = r_bias[(tid + 1) * Nh + n] * ATT_SCALE;
        __builtin_amdgcn_global_load_lds((const AS1 void*)srcK, (AS3 void*)&sKa[0][wave * 512], 16, 0, 0);
        __builtin_amdgcn_global_load_lds((const AS1 void*)srcE, (AS3 void*)&sKe[0][wave * 512], 16, 0, 0);
        __builtin_amdgcn_global_load_lds((const AS1 void*)srcV, (AS3 void*)&sVa[0][wave * 512], 16, 0, 0);
        if (tid < 64) sRB[0][tid] = rbv;
    }
    __syncthreads();   // drains vmcnt(0): tile 0 resident

    for (int jt = 0; jt < 16; ++jt) {
        const int cur = jt & 1;

        // issue next tile's async loads FIRST (in flight across compute below)
        float rbn = 0.0f;
        if (jt < 15) {
            const int j0n = (jt + 1) * 64;
            __builtin_amdgcn_global_load_lds((const AS1 void*)(srcK + (long)j0n * 1024),
                                             (AS3 void*)&sKa[cur ^ 1][wave * 512], 16, 0, 0);
            __builtin_amdgcn_global_load_lds((const AS1 void*)(srcE + (long)j0n * 64),
                                             (AS3 void*)&sKe[cur ^ 1][wave * 512], 16, 0, 0);
            __builtin_amdgcn_global_load_lds((const AS1 void*)(srcV + j0n),
                                             (AS3 void*)&sVa[cur ^ 1][wave * 512], 16, 0, 0);
            if (tid < 64) {
                int j = j0n + tid;
                rbn = (j < Qc - 1) ? r_bias[(j + 1) * Nh + n] * ATT_SCALE : 0.0f;
            }
        }

        const f16* Ka = &sKa[cur][0];
        const f16* Kb = &sKe[cur][0];
        const f16* Va = &sVa[cur][0];
        const int rsw = lrow & 7;

        // S^T: D[m=j][n=q], 64 j x 16 q per wave; K=128 (kh | Ke)
        f32x4 s_acc[4] = {};
#pragma unroll
        for (int ni = 0; ni < 4; ++ni) {
            int rb_ = (ni * 16 + lrow) * 64;
            f16x8 a0 = *(const f16x8*)&Ka[rb_ + ((0 + quad) ^ rsw) * 8];
            f16x8 a1 = *(const f16x8*)&Ka[rb_ + ((4 + quad) ^ rsw) * 8];
            f16x8 e0 = *(const f16x8*)&Kb[rb_ + ((0 + quad) ^ rsw) * 8];
            f16x8 e1 = *(const f16x8*)&Kb[rb_ + ((4 + quad) ^ rsw) * 8];
            s_acc[ni] = __builtin_amdgcn_mfma_f32_16x16x32_f16(a0, aq[0], s_acc[ni], 0, 0, 0);
            s_acc[ni] = __builtin_amdgcn_mfma_f32_16x16x32_f16(a1, aq[1], s_acc[ni], 0, 0, 0);
            s_acc[ni] = __builtin_amdgcn_mfma_f32_16x16x32_f16(e0, aq[2], s_acc[ni], 0, 0, 0);
            s_acc[ni] = __builtin_amdgcn_mfma_f32_16x16x32_f16(e1, aq[3], s_acc[ni], 0, 0, 0);
        }

        // online softmax per q (= lane&15); 16 S values/lane
        f16x4 pf[4];
        float mx = -1e30f;
#pragma unroll
        for (int ni = 0; ni < 4; ++ni) {
            f32x4 rb4 = *(const f32x4*)&sRB[cur][ni * 16 + quad * 4];
#pragma unroll
            for (int r = 0; r < 4; ++r) {
                float v = s_acc[ni][r] + rb4[r];   // scale pre-folded
                s_acc[ni][r] = v;
                mx = fmaxf(mx, v);
            }
        }
        mx = fmaxf(mx, __shfl_xor(mx, 16));
        mx = fmaxf(mx, __shfl_xor(mx, 32));
        float mn = fmaxf(m_i, mx);
        float alpha = __expf(m_i - mn);
        float sm = 0.0f;
#pragma unroll
        for (int ni = 0; ni < 4; ++ni) {
            float e0 = __expf(s_acc[ni][0] - mn);
            float e1 = __expf(s_acc[ni][1] - mn);
            float e2 = __expf(s_acc[ni][2] - mn);
            float e3 = __expf(s_acc[ni][3] - mn);
            sm += (e0 + e1) + (e2 + e3);
            f16x4 pvv; pvv[0] = (f16)e0; pvv[1] = (f16)e1; pvv[2] = (f16)e2; pvv[3] = (f16)e3;
            pf[ni] = pvv;
        }
        sm += __shfl_xor(sm, 16);
        sm += __shfl_xor(sm, 32);
        l_i = l_i * alpha + sm;
        m_i = mn;

        // rescale o_acc: broadcast alpha from lane (quad*4+r) of the q-group
#pragma unroll
        for (int r = 0; r < 4; ++r) {
            float al = __shfl(alpha, quad * 4 + r);
#pragma unroll
            for (int dt = 0; dt < 4; ++dt) o_acc[dt][r] *= al;
        }

        // PV: D[m=q][n=d] += P[q][j] * V[j][d], K=16 chunks, P from registers.
        // sVa read with source-matched swizzle (16B chunk ^ (d&7)).
#pragma unroll
        for (int nj = 0; nj < 4; ++nj) {
            int coff = ((2 * nj + (quad >> 1)) ^ rsw) * 8 + (quad & 1) * 4;
#pragma unroll
            for (int dt = 0; dt < 4; ++dt) {
                f16x4 bv = *(const f16x4*)&Va[(dt * 16 + lrow) * 64 + coff];
                o_acc[dt] = __builtin_amdgcn_mfma_f32_16x16x16f16(pf[nj], bv, o_acc[dt], 0, 0, 0);
            }
        }

        if (jt < 15) {
            if (tid < 64) sRB[cur ^ 1][tid] = rbn;
            __syncthreads();   // drains vmcnt: next tile resident; rb visible
        }
    }

    // epilogue: avp[b][i][n*64+d] = O / l  (row q=quad*4+r, col d=lane&15)
    {
        float linv = 1.0f / l_i;
#pragma unroll
        for (int r = 0; r < 4; ++r) {
            float li = __shfl(linv, quad * 4 + r);
            int i = i0 + wave * 16 + quad * 4 + r;
#pragma unroll
            for (int dt = 0; dt < 4; ++dt) {
                int d = dt * 16 + lrow;
                avp[((long)(b * Qc + i) << 10) + n * 64 + d] = (f16)(o_acc[dt][r] * li);
            }
        }
    }
}

// ---------------- residual + LayerNorm (w f32, ao f16; f32 output) ----------------
__global__ __launch_bounds__(256) void k_res_ln(const float* __restrict__ w, const f16* __restrict__ ao,
                                                const float* __restrict__ gamma, const float* __restrict__ beta,
                                                float* __restrict__ out) {
    const long base = (long)blockIdx.x * 1024;
    const int tid = threadIdx.x;
    float4 wv = *(const float4*)&w[base + tid * 4];
    f16x4 av = *(const f16x4*)&ao[base + tid * 4];
    float x[4] = { wv.x + (float)av[0], wv.y + (float)av[1],
                   wv.z + (float)av[2], wv.w + (float)av[3] };
    float s = x[0] + x[1] + x[2] + x[3];
    float s2 = x[0] * x[0] + x[1] * x[1] + x[2] * x[2] + x[3] * x[3];
#pragma unroll
    for (int off = 32; off; off >>= 1) { s += __shfl_down(s, off); s2 += __shfl_down(s2, off); }
    __shared__ float rs[4], rs2[4];
    if ((tid & 63) == 0) { rs[tid >> 6] = s; rs2[tid >> 6] = s2; }
    __syncthreads();
    s = rs[0] + rs[1] + rs[2] + rs[3];
    s2 = rs2[0] + rs2[1] + rs2[2] + rs2[3];
    float mu = s * (1.0f / 1024.0f);
    float var = s2 * (1.0f / 1024.0f) - mu * mu;
    float inv = rsqrtf(var + 1e-5f);
    float4 gv = *(const float4*)&gamma[tid * 4];
    float4 bv = *(const float4*)&beta[tid * 4];
    float4 o;
    o.x = (x[0] - mu) * inv * gv.x + bv.x;
    o.y = (x[1] - mu) * inv * gv.y + bv.y;
    o.z = (x[2] - mu) * inv * gv.z + bv.z;
    o.w = (x[3] - mu) * inv * gv.w + bv.w;
    *(float4*)&out[base + tid * 4] = o;
}

extern "C" void kernel_launch(void* const* d_in, const int* in_sizes, int n_in,
                              void* d_out, int out_size, void* d_ws, size_t ws_size,
                              hipStream_t stream) {
    const float* w_in   = (const float*)d_in[0];
    const float* r_emb  = (const float*)d_in[1];
    const float* r_wb   = (const float*)d_in[2];
    const float* r_bias = (const float*)d_in[3];
    const float* Wq     = (const float*)d_in[4];
    const float* Wk     = (const float*)d_in[5];
    const float* Wv     = (const float*)d_in[6];
    const float* Wo     = (const float*)d_in[7];
    const float* ln_g   = (const float*)d_in[8];
    const float* ln_b   = (const float*)d_in[9];
    float* out = (float*)d_out;

    // workspace carve-out (48MB fixed + aliases)
    char* p = (char*)d_ws;
    auto alloc = [&](size_t bytes) { char* r = p; p += (bytes + 255) & ~(size_t)255; return r; };
    f16* wh = (f16*)alloc((size_t)BQ * Dc * 2);          // 8 MB
    f16* WT = (f16*)alloc((size_t)4 * Dc * Dc * 2);      // 8 MB: WqT,WkT,WvT,WoT (contiguous)
    f16* qh = (f16*)alloc((size_t)BQ * Dc * 2);          // 8 MB [b*Q+i][n*64+d]
    f16* kh = (f16*)alloc((size_t)BQ * Dc * 2);          // 8 MB [b*Q+j][n*64+d]
    f16* Ke = (f16*)alloc((size_t)NHEAD * Qc * DHc * 2); // 8 MB [h][j][64] rel-shifted r_emb
    f16* vT = (f16*)alloc((size_t)BQ * Dc * 2);          // 8 MB [b][dcol][j]
    f16* WoT = WT + (size_t)3 * Dc * Dc;
    // aliases (liveness-checked): wh dead after QKV GEMM; Ke dead after flash
    f16* avp = wh;                 // [b][i][1024] f16
    f16* ao  = Ke;                 // 8 MB f16

    // 1. f32->f16 of w (8/thread)
    k_f2h<<<(BQ * Dc) / (256 * 8), 256, 0, stream>>>(w_in, wh);

    // 2. transpose 4 weights in one dispatch (f32 -> f16)
    Ptr4 srcs{{Wq, Wk, Wv, Wo}};
    k_transpose4<<<dim3(32, 32, 4), dim3(32, 8), 0, stream>>>(srcs, WT);

    // 3. rel-shifted r_emb -> Ke (independent of GEMMs)
    k_fill_remb<<<(NHEAD * Qc * 8) / 256, 256, 0, stream>>>(r_emb, Ke);

    // 4. fused QKV projection: N=3072; seg0/1 natural row-major, seg2 vT scatter
    k_gemm_nt<128, 128, 32, 2, 2, 5><<<dim3(3 * Dc / 128, BQ / 128), 256, 0, stream>>>(
        wh, WT, nullptr, qh, kh, vT, Dc, Dc, 0, Dc);

    // 5. fused attention (XCD-swizzled 1D grid 512, 8-wave blocks, async dbuf)
    k_flash<<<512, 512, 0, stream>>>(qh, kh, Ke, vT, r_wb, r_bias, avp);

    // 6. attn_out = avp @ Wo^T (64x128 tile -> 512 blocks; f16 out into aliased ao)
    k_gemm_nt<64, 128, 32, 2, 2, 0><<<dim3(Dc / 128, BQ / 64), 256, 0, stream>>>(
        avp, WoT, ao, nullptr, nullptr, nullptr, Dc, Dc, Dc, Dc);

    // 7. out = LayerNorm(w + attn_out), fp32 output
    k_res_ln<<<BQ, 256, 0, stream>>>(w_in, ao, ln_g, ln_b, out);
}

// Round 5
// 213.702 us; speedup vs baseline: 1.0271x; 1.0136x over previous
//
#include <hip/hip_runtime.h>
#include <hip/hip_bf16.h>

using f16 = _Float16;
typedef _Float16 f16x8 __attribute__((ext_vector_type(8)));
typedef _Float16 f16x4 __attribute__((ext_vector_type(4)));
typedef float f32x4 __attribute__((ext_vector_type(4)));

#define AS1 __attribute__((address_space(1)))
#define AS3 __attribute__((address_space(3)))

// Problem constants
constexpr int Bc = 4, Qc = 1024, Dc = 1024, Nh = 16, DHc = 64;
constexpr int BQ = Bc * Qc;      // 4096 rows of w
constexpr int NHEAD = Bc * Nh;   // 64 (b,n) heads
constexpr float ATT_SCALE = 0.125f;
constexpr float LOG2E = 1.44269504088896f;

// ---------------- f32 -> f16, 8 elems/thread ----------------
__global__ void k_f2h(const float* __restrict__ src, f16* __restrict__ dst) {
    long i8 = ((long)blockIdx.x * blockDim.x + threadIdx.x) * 8;
    float4 a = *(const float4*)&src[i8];
    float4 b = *(const float4*)&src[i8 + 4];
    f16x8 o = { (f16)a.x, (f16)a.y, (f16)a.z, (f16)a.w,
                (f16)b.x, (f16)b.y, (f16)b.z, (f16)b.w };
    *(f16x8*)&dst[i8] = o;
}

// ---------------- merged 4-way weight transpose: src[z][R][C] -> dst[z][C][R] f16 ----------------
struct Ptr4 { const float* p[4]; };
__global__ void k_transpose4(Ptr4 srcs, f16* __restrict__ dst) {
    __shared__ f16 tile[32][33];
    const float* src = srcs.p[blockIdx.z];
    f16* d = dst + (long)blockIdx.z * Dc * Dc;
    int c0 = blockIdx.x * 32, r0 = blockIdx.y * 32;
#pragma unroll
    for (int dy = 0; dy < 32; dy += 8) {
        int r = r0 + threadIdx.y + dy, c = c0 + threadIdx.x;
        tile[threadIdx.y + dy][threadIdx.x] = (f16)src[(long)r * Dc + c];
    }
    __syncthreads();
#pragma unroll
    for (int dy = 0; dy < 32; dy += 8) {
        int c = c0 + threadIdx.y + dy, r = r0 + threadIdx.x;
        d[(long)c * Dc + r] = tile[threadIdx.x][threadIdx.y + dy];
    }
}

// ---------------- Ke[h][j][0:64] = r_emb[j+1][n][:] (0 at j=1023) ----------------
__global__ void k_fill_remb(const float* __restrict__ remb, f16* __restrict__ Ke) {
    long gid = (long)blockIdx.x * blockDim.x + threadIdx.x;  // 64*1024*8
    int d8 = (int)(gid & 7) * 8;
    int j = (int)((gid >> 3) & 1023);
    int h = (int)(gid >> 13);
    int n = h & 15;
    f16x8 kv;
    if (j < 1023) {
        const float* rp = &remb[((long)(j + 1) * 16 + n) * 64 + d8];
        float4 r0 = *(const float4*)rp, r1 = *(const float4*)(rp + 4);
        kv[0] = (f16)r0.x; kv[1] = (f16)r0.y; kv[2] = (f16)r0.z; kv[3] = (f16)r0.w;
        kv[4] = (f16)r1.x; kv[5] = (f16)r1.y; kv[6] = (f16)r1.z; kv[7] = (f16)r1.w;
    } else {
        kv = f16x8{};
    }
    *(f16x8*)&Ke[(((long)h << 10) + j) * 64 + d8] = kv;
}

// ---------------- NT GEMM, global_load_lds staging, fused epilogues ----------------
// EPI: 0 = f16 row-major; 5 = QKV: seg0/1 natural row-major to qtp/ktp, seg2 vT scatter.
// R5: XCD-chunked block swizzle (T1) — grids are multiples of 8 (QKV 768, Wo 512),
// so swz = (flat&7)*(nwg/8) + flat>>3 is bijective; each XCD gets a contiguous
// tile range sharing A row-panels in its private L2.
template <int BM, int BN, int BK, int WROWS, int WCOLS, int EPI>
__global__ __launch_bounds__(256) void k_gemm_nt(
    const f16* __restrict__ A, const f16* __restrict__ Bt, void* __restrict__ Cv,
    f16* __restrict__ qtp, f16* __restrict__ ktp, f16* __restrict__ vtp,
    int lda, int ldb, int ldc, int K)
{
    constexpr int TM = BM / (WROWS * 16);
    constexpr int TN = BN / (WCOLS * 16);
    __shared__ __align__(16) f16 sA[BM * BK];
    __shared__ __align__(16) f16 sB[BN * BK];

    const int tid = threadIdx.x;
    const int lane = tid & 63, wave = tid >> 6;
    const int wm = wave / WCOLS, wn = wave % WCOLS;

    const int nwg = gridDim.x * gridDim.y;
    const int flat = blockIdx.y * gridDim.x + blockIdx.x;
    const int cpx = nwg >> 3;
    const int swz = (flat & 7) * cpx + (flat >> 3);
    const int bx = swz % gridDim.x, by = swz / gridDim.x;
    const int m0 = by * BM, n0 = bx * BN;

    f32x4 acc[TM][TN] = {};

    const int lrow = lane & 15;
    const int kq = (lane >> 4) * 8;
    const int srow = lane >> 2;            // 16 rows per 1KB chunk
    const int scol = (lane & 3) * 8;       // 4 lanes x 8 f16 per 64B row

    for (int k0 = 0; k0 < K; k0 += BK) {
        __syncthreads();
        constexpr int CHA = BM * BK / 512;   // 1KB chunks
#pragma unroll
        for (int ch = 0; ch < CHA / 4; ++ch) {
            int cc = ch * 4 + wave;
            __builtin_amdgcn_global_load_lds(
                (const AS1 void*)(const void*)&A[(long)(m0 + cc * 16 + srow) * lda + k0 + scol],
                (AS3 void*)(void*)&sA[cc * 512], 16, 0, 0);
        }
        constexpr int CHB = BN * BK / 512;
#pragma unroll
        for (int ch = 0; ch < CHB / 4; ++ch) {
            int cc = ch * 4 + wave;
            __builtin_amdgcn_global_load_lds(
                (const AS1 void*)(const void*)&Bt[(long)(n0 + cc * 16 + srow) * ldb + k0 + scol],
                (AS3 void*)(void*)&sB[cc * 512], 16, 0, 0);
        }
        __syncthreads();

        f16x8 af[TM], bfr[TN];
#pragma unroll
        for (int mi = 0; mi < TM; ++mi)
            af[mi] = *(const f16x8*)&sA[(wm * TM * 16 + mi * 16 + lrow) * BK + kq];
#pragma unroll
        for (int ni = 0; ni < TN; ++ni)
            bfr[ni] = *(const f16x8*)&sB[(wn * TN * 16 + ni * 16 + lrow) * BK + kq];
#pragma unroll
        for (int mi = 0; mi < TM; ++mi)
#pragma unroll
            for (int ni = 0; ni < TN; ++ni)
                acc[mi][ni] = __builtin_amdgcn_mfma_f32_16x16x32_f16(af[mi], bfr[ni], acc[mi][ni], 0, 0, 0);
    }

    const int crow = (lane >> 4) * 4;
    const int ccol = lane & 15;
#pragma unroll
    for (int mi = 0; mi < TM; ++mi)
#pragma unroll
        for (int ni = 0; ni < TN; ++ni)
#pragma unroll
            for (int r = 0; r < 4; ++r) {
                int gm = m0 + wm * TM * 16 + mi * 16 + crow + r;
                int gn = n0 + wn * TN * 16 + ni * 16 + ccol;
                float val = acc[mi][ni][r];
                if constexpr (EPI == 0) {
                    ((f16*)Cv)[(long)gm * ldc + gn] = (f16)val;
                } else {
                    int seg = n0 >> 10;       // block-uniform (BN=128 | 1024)
                    int col = gn & 1023;
                    if (seg == 0) {
                        qtp[(long)gm * 1024 + col] = (f16)val;
                    } else if (seg == 1) {
                        ktp[(long)gm * 1024 + col] = (f16)val;
                    } else {
                        int b = gm >> 10, i = gm & 1023;
                        vtp[(((long)(b << 10) + col) << 10) + i] = (f16)val;
                    }
                }
            }
}

// ---------------- fused flash attention v11: v10 + log2-domain softmax.
// __expf = v_mul + v_exp; folding log2e into the bias-add fma and using raw
// exp2 removes 17 VALU ops/lane/iter from the busiest pipe (VALUBusy 43.5%).
// rb staged pre-scaled by ATT_SCALE*LOG2E; per-element v = fma(s, LOG2E, rb);
// all exps are __builtin_amdgcn_exp2f. Q fragments keep exact *0.125 (f16).
// Base change cancels in P/l normalization -> mathematically equivalent.
// Tripwires: WRITE_SIZE == 8192 KB, VGPR <= 64 (no spill); FETCH ~16.7MB;
// absmax may move in the last bit, revert if > ~0.06.
__global__ __launch_bounds__(512, 4) void k_flash(
    const f16* __restrict__ qh, const f16* __restrict__ kh,
    const f16* __restrict__ Ke, const f16* __restrict__ vT,
    const float* __restrict__ rwb, const float* __restrict__ r_bias,
    f16* __restrict__ avp)
{
    __shared__ __align__(16) f16 sKa[2][64 * 64];   // kh tile: [j-local][d]
    __shared__ __align__(16) f16 sKe[2][64 * 64];   // Ke tile: [j-local][d]
    __shared__ __align__(16) f16 sVa[2][64 * 64];   // vT tile: [d][j-local]
    __shared__ float sRB[2][64];

    const int tid = threadIdx.x, lane = tid & 63, wave = tid >> 6;  // wave 0..7
    const int bid = blockIdx.x;
    const int h = (((bid >> 3) & 7) << 3) | (bid & 7);
    const int i0 = (bid >> 6) * 128;
    const int b = h >> 4, n = h & 15;

    const int lrow = lane & 15;            // q (B-frag n) / row index
    const int quad = lane >> 4;
    const int lr3 = lane >> 3;             // staging: row within wave's 8-row slice
    const int swc = (lane & 7) ^ (lr3 & 7);  // inverse-swizzled source 16B chunk

    // wave-slice per-lane source pointers (tile row = 8*wave + lr3)
    const f16* srcK = kh + ((long)(b * Qc) + 8 * wave + lr3) * 1024 + n * 64 + swc * 8;
    const f16* srcE = Ke + ((long)h * Qc + 8 * wave + lr3) * 64 + swc * 8;
    const f16* srcV = vT + (long)h * DHc * Qc + (long)(8 * wave + lr3) * Qc + swc * 8;

    // r_w_bias fragments (f32 -> f16), pre-scaled by ATT_SCALE
    f16x8 rw0, rw1;
#pragma unroll
    for (int e = 0; e < 8; ++e) {
        rw0[e] = (f16)(rwb[n * 64 + quad * 8 + e] * ATT_SCALE);
        rw1[e] = (f16)(rwb[n * 64 + 32 + quad * 8 + e] * ATT_SCALE);
    }

    // Q fragments (B-operand of S^T): wave owns q rows [i0+wave*16, +16).
    const f16 qsc = (f16)0.125f;
    f16x8 aq[4];
    {
        long rix = (long)(b * Qc + i0 + wave * 16 + lrow) * 1024 + n * 64;
        f16x8 q0 = *(const f16x8*)&qh[rix + quad * 8] * qsc;
        f16x8 q1 = *(const f16x8*)&qh[rix + 32 + quad * 8] * qsc;
        aq[0] = q0 + rw0;   // k-dim [0,32):  (q + r_w_bias) * scale, dot kh
        aq[1] = q1 + rw1;   // k-dim [32,64)
        aq[2] = q0;         // k-dim [64,96):  q * scale, dot Ke
        aq[3] = q1;         // k-dim [96,128)
    }

    float m_i = -1e30f, l_i = 0.0f;   // m in log2 domain
    f32x4 o_acc[4] = {};   // D[m=q][n=d]: row q=quad*4+reg, col d=lane&15

    // prologue: stage tile 0 (async) + rb0
    {
        float rbv = 0.0f;
        if (tid < 64) rbv = r_bias[(tid + 1) * Nh + n] * (ATT_SCALE * LOG2E);
        __builtin_amdgcn_global_load_lds((const AS1 void*)srcK, (AS3 void*)&sKa[0][wave * 512], 16, 0, 0);
        __builtin_amdgcn_global_load_lds((const AS1 void*)srcE, (AS3 void*)&sKe[0][wave * 512], 16, 0, 0);
        __builtin_amdgcn_global_load_lds((const AS1 void*)srcV, (AS3 void*)&sVa[0][wave * 512], 16, 0, 0);
        if (tid < 64) sRB[0][tid] = rbv;
    }
    __syncthreads();   // drains vmcnt(0): tile 0 resident

    for (int jt = 0; jt < 16; ++jt) {
        const int cur = jt & 1;

        // issue next tile's async loads FIRST (in flight across compute below)
        float rbn = 0.0f;
        if (jt < 15) {
            const int j0n = (jt + 1) * 64;
            __builtin_amdgcn_global_load_lds((const AS1 void*)(srcK + (long)j0n * 1024),
                                             (AS3 void*)&sKa[cur ^ 1][wave * 512], 16, 0, 0);
            __builtin_amdgcn_global_load_lds((const AS1 void*)(srcE + (long)j0n * 64),
                                             (AS3 void*)&sKe[cur ^ 1][wave * 512], 16, 0, 0);
            __builtin_amdgcn_global_load_lds((const AS1 void*)(srcV + j0n),
                                             (AS3 void*)&sVa[cur ^ 1][wave * 512], 16, 0, 0);
            if (tid < 64) {
                int j = j0n + tid;
                rbn = (j < Qc - 1) ? r_bias[(j + 1) * Nh + n] * (ATT_SCALE * LOG2E) : 0.0f;
            }
        }

        const f16* Ka = &sKa[cur][0];
        const f16* Kb = &sKe[cur][0];
        const f16* Va = &sVa[cur][0];
        const int rsw = lrow & 7;

        // S^T: D[m=j][n=q], 64 j x 16 q per wave; K=128 (kh | Ke)
        f32x4 s_acc[4] = {};
#pragma unroll
        for (int ni = 0; ni < 4; ++ni) {
            int rb_ = (ni * 16 + lrow) * 64;
            f16x8 a0 = *(const f16x8*)&Ka[rb_ + ((0 + quad) ^ rsw) * 8];
            f16x8 a1 = *(const f16x8*)&Ka[rb_ + ((4 + quad) ^ rsw) * 8];
            f16x8 e0 = *(const f16x8*)&Kb[rb_ + ((0 + quad) ^ rsw) * 8];
            f16x8 e1 = *(const f16x8*)&Kb[rb_ + ((4 + quad) ^ rsw) * 8];
            s_acc[ni] = __builtin_amdgcn_mfma_f32_16x16x32_f16(a0, aq[0], s_acc[ni], 0, 0, 0);
            s_acc[ni] = __builtin_amdgcn_mfma_f32_16x16x32_f16(a1, aq[1], s_acc[ni], 0, 0, 0);
            s_acc[ni] = __builtin_amdgcn_mfma_f32_16x16x32_f16(e0, aq[2], s_acc[ni], 0, 0, 0);
            s_acc[ni] = __builtin_amdgcn_mfma_f32_16x16x32_f16(e1, aq[3], s_acc[ni], 0, 0, 0);
        }

        // online softmax per q (= lane&15), log2 domain; v = fma(s, log2e, rb)
        f16x4 pf[4];
        float mx = -1e30f;
#pragma unroll
        for (int ni = 0; ni < 4; ++ni) {
            f32x4 rb4 = *(const f32x4*)&sRB[cur][ni * 16 + quad * 4];
#pragma unroll
            for (int r = 0; r < 4; ++r) {
                float v = fmaf(s_acc[ni][r], LOG2E, rb4[r]);
                s_acc[ni][r] = v;
                mx = fmaxf(mx, v);
            }
        }
        mx = fmaxf(mx, __shfl_xor(mx, 16));
        mx = fmaxf(mx, __shfl_xor(mx, 32));
        float mn = fmaxf(m_i, mx);
        float alpha = __builtin_amdgcn_exp2f(m_i - mn);
        float sm = 0.0f;
#pragma unroll
        for (int ni = 0; ni < 4; ++ni) {
            float e0 = __builtin_amdgcn_exp2f(s_acc[ni][0] - mn);
            float e1 = __builtin_amdgcn_exp2f(s_acc[ni][1] - mn);
            float e2 = __builtin_amdgcn_exp2f(s_acc[ni][2] - mn);
            float e3 = __builtin_amdgcn_exp2f(s_acc[ni][3] - mn);
            sm += (e0 + e1) + (e2 + e3);
            f16x4 pvv; pvv[0] = (f16)e0; pvv[1] = (f16)e1; pvv[2] = (f16)e2; pvv[3] = (f16)e3;
            pf[ni] = pvv;
        }
        sm += __shfl_xor(sm, 16);
        sm += __shfl_xor(sm, 32);
        l_i = l_i * alpha + sm;
        m_i = mn;

        // rescale o_acc: broadcast alpha from lane (quad*4+r) of the q-group
#pragma unroll
        for (int r = 0; r < 4; ++r) {
            float al = __shfl(alpha, quad * 4 + r);
#pragma unroll
            for (int dt = 0; dt < 4; ++dt) o_acc[dt][r] *= al;
        }

        // PV: D[m=q][n=d] += P[q][j] * V[j][d], K=16 chunks, P from registers.
        // sVa read with source-matched swizzle (16B chunk ^ (d&7)).
#pragma unroll
        for (int nj = 0; nj < 4; ++nj) {
            int coff = ((2 * nj + (quad >> 1)) ^ rsw) * 8 + (quad & 1) * 4;
#pragma unroll
            for (int dt = 0; dt < 4; ++dt) {
                f16x4 bv = *(const f16x4*)&Va[(dt * 16 + lrow) * 64 + coff];
                o_acc[dt] = __builtin_amdgcn_mfma_f32_16x16x16f16(pf[nj], bv, o_acc[dt], 0, 0, 0);
            }
        }

        if (jt < 15) {
            if (tid < 64) sRB[cur ^ 1][tid] = rbn;
            __syncthreads();   // drains vmcnt: next tile resident; rb visible
        }
    }

    // epilogue: avp[b][i][n*64+d] = O / l  (row q=quad*4+r, col d=lane&15)
    {
        float linv = 1.0f / l_i;
#pragma unroll
        for (int r = 0; r < 4; ++r) {
            float li = __shfl(linv, quad * 4 + r);
            int i = i0 + wave * 16 + quad * 4 + r;
#pragma unroll
            for (int dt = 0; dt < 4; ++dt) {
                int d = dt * 16 + lrow;
                avp[((long)(b * Qc + i) << 10) + n * 64 + d] = (f16)(o_acc[dt][r] * li);
            }
        }
    }
}

// ---------------- residual + LayerNorm (w f32, ao f16; f32 output) ----------------
__global__ __launch_bounds__(256) void k_res_ln(const float* __restrict__ w, const f16* __restrict__ ao,
                                                const float* __restrict__ gamma, const float* __restrict__ beta,
                                                float* __restrict__ out) {
    const long base = (long)blockIdx.x * 1024;
    const int tid = threadIdx.x;
    float4 wv = *(const float4*)&w[base + tid * 4];
    f16x4 av = *(const f16x4*)&ao[base + tid * 4];
    float x[4] = { wv.x + (float)av[0], wv.y + (float)av[1],
                   wv.z + (float)av[2], wv.w + (float)av[3] };
    float s = x[0] + x[1] + x[2] + x[3];
    float s2 = x[0] * x[0] + x[1] * x[1] + x[2] * x[2] + x[3] * x[3];
#pragma unroll
    for (int off = 32; off; off >>= 1) { s += __shfl_down(s, off); s2 += __shfl_down(s2, off); }
    __shared__ float rs[4], rs2[4];
    if ((tid & 63) == 0) { rs[tid >> 6] = s; rs2[tid >> 6] = s2; }
    __syncthreads();
    s = rs[0] + rs[1] + rs[2] + rs[3];
    s2 = rs2[0] + rs2[1] + rs2[2] + rs2[3];
    float mu = s * (1.0f / 1024.0f);
    float var = s2 * (1.0f / 1024.0f) - mu * mu;
    float inv = rsqrtf(var + 1e-5f);
    float4 gv = *(const float4*)&gamma[tid * 4];
    float4 bv = *(const float4*)&beta[tid * 4];
    float4 o;
    o.x = (x[0] - mu) * inv * gv.x + bv.x;
    o.y = (x[1] - mu) * inv * gv.y + bv.y;
    o.z = (x[2] - mu) * inv * gv.z + bv.z;
    o.w = (x[3] - mu) * inv * gv.w + bv.w;
    *(float4*)&out[base + tid * 4] = o;
}

extern "C" void kernel_launch(void* const* d_in, const int* in_sizes, int n_in,
                              void* d_out, int out_size, void* d_ws, size_t ws_size,
                              hipStream_t stream) {
    const float* w_in   = (const float*)d_in[0];
    const float* r_emb  = (const float*)d_in[1];
    const float* r_wb   = (const float*)d_in[2];
    const float* r_bias = (const float*)d_in[3];
    const float* Wq     = (const float*)d_in[4];
    const float* Wk     = (const float*)d_in[5];
    const float* Wv     = (const float*)d_in[6];
    const float* Wo     = (const float*)d_in[7];
    const float* ln_g   = (const float*)d_in[8];
    const float* ln_b   = (const float*)d_in[9];
    float* out = (float*)d_out;

    // workspace carve-out (48MB fixed + aliases)
    char* p = (char*)d_ws;
    auto alloc = [&](size_t bytes) { char* r = p; p += (bytes + 255) & ~(size_t)255; return r; };
    f16* wh = (f16*)alloc((size_t)BQ * Dc * 2);          // 8 MB
    f16* WT = (f16*)alloc((size_t)4 * Dc * Dc * 2);      // 8 MB: WqT,WkT,WvT,WoT (contiguous)
    f16* qh = (f16*)alloc((size_t)BQ * Dc * 2);          // 8 MB [b*Q+i][n*64+d]
    f16* kh = (f16*)alloc((size_t)BQ * Dc * 2);          // 8 MB [b*Q+j][n*64+d]
    f16* Ke = (f16*)alloc((size_t)NHEAD * Qc * DHc * 2); // 8 MB [h][j][64] rel-shifted r_emb
    f16* vT = (f16*)alloc((size_t)BQ * Dc * 2);          // 8 MB [b][dcol][j]
    f16* WoT = WT + (size_t)3 * Dc * Dc;
    // aliases (liveness-checked): wh dead after QKV GEMM; Ke dead after flash
    f16* avp = wh;                 // [b][i][1024] f16
    f16* ao  = Ke;                 // 8 MB f16

    // 1. f32->f16 of w (8/thread)
    k_f2h<<<(BQ * Dc) / (256 * 8), 256, 0, stream>>>(w_in, wh);

    // 2. transpose 4 weights in one dispatch (f32 -> f16)
    Ptr4 srcs{{Wq, Wk, Wv, Wo}};
    k_transpose4<<<dim3(32, 32, 4), dim3(32, 8), 0, stream>>>(srcs, WT);

    // 3. rel-shifted r_emb -> Ke (independent of GEMMs)
    k_fill_remb<<<(NHEAD * Qc * 8) / 256, 256, 0, stream>>>(r_emb, Ke);

    // 4. fused QKV projection: N=3072; seg0/1 natural row-major, seg2 vT scatter
    k_gemm_nt<128, 128, 32, 2, 2, 5><<<dim3(3 * Dc / 128, BQ / 128), 256, 0, stream>>>(
        wh, WT, nullptr, qh, kh, vT, Dc, Dc, 0, Dc);

    // 5. fused attention (XCD-swizzled 1D grid 512, 8-wave blocks, async dbuf)
    k_flash<<<512, 512, 0, stream>>>(qh, kh, Ke, vT, r_wb, r_bias, avp);

    // 6. attn_out = avp @ Wo^T (64x128 tile -> 512 blocks; f16 out into aliased ao)
    k_gemm_nt<64, 128, 32, 2, 2, 0><<<dim3(Dc / 128, BQ / 64), 256, 0, stream>>>(
        avp, WoT, ao, nullptr, nullptr, nullptr, Dc, Dc, Dc, Dc);

    // 7. out = LayerNorm(w + attn_out), fp32 output
    k_res_ln<<<BQ, 256, 0, stream>>>(w_in, ao, ln_g, ln_b, out);
}

// Round 6
// 203.396 us; speedup vs baseline: 1.0792x; 1.0507x over previous
//
#include <hip/hip_runtime.h>
#include <hip/hip_bf16.h>

using f16 = _Float16;
typedef _Float16 f16x8 __attribute__((ext_vector_type(8)));
typedef _Float16 f16x4 __attribute__((ext_vector_type(4)));
typedef float f32x4 __attribute__((ext_vector_type(4)));

#define AS1 __attribute__((address_space(1)))
#define AS3 __attribute__((address_space(3)))

// Problem constants
constexpr int Bc = 4, Qc = 1024, Dc = 1024, Nh = 16, DHc = 64;
constexpr int BQ = Bc * Qc;      // 4096 rows of w
constexpr int NHEAD = Bc * Nh;   // 64 (b,n) heads
constexpr float ATT_SCALE = 0.125f;
constexpr float LOG2E = 1.44269504088896f;

// ---------------- f32 -> f16, 8 elems/thread ----------------
__global__ void k_f2h(const float* __restrict__ src, f16* __restrict__ dst) {
    long i8 = ((long)blockIdx.x * blockDim.x + threadIdx.x) * 8;
    float4 a = *(const float4*)&src[i8];
    float4 b = *(const float4*)&src[i8 + 4];
    f16x8 o = { (f16)a.x, (f16)a.y, (f16)a.z, (f16)a.w,
                (f16)b.x, (f16)b.y, (f16)b.z, (f16)b.w };
    *(f16x8*)&dst[i8] = o;
}

// ---------------- merged 4-way weight transpose: src[z][R][C] -> dst[z][C][R] f16 ----------------
struct Ptr4 { const float* p[4]; };
__global__ void k_transpose4(Ptr4 srcs, f16* __restrict__ dst) {
    __shared__ f16 tile[32][33];
    const float* src = srcs.p[blockIdx.z];
    f16* d = dst + (long)blockIdx.z * Dc * Dc;
    int c0 = blockIdx.x * 32, r0 = blockIdx.y * 32;
#pragma unroll
    for (int dy = 0; dy < 32; dy += 8) {
        int r = r0 + threadIdx.y + dy, c = c0 + threadIdx.x;
        tile[threadIdx.y + dy][threadIdx.x] = (f16)src[(long)r * Dc + c];
    }
    __syncthreads();
#pragma unroll
    for (int dy = 0; dy < 32; dy += 8) {
        int c = c0 + threadIdx.y + dy, r = r0 + threadIdx.x;
        d[(long)c * Dc + r] = tile[threadIdx.x][threadIdx.y + dy];
    }
}

// ---------------- Ke[h][j][0:64] = r_emb[j+1][n][:] (0 at j=1023) ----------------
__global__ void k_fill_remb(const float* __restrict__ remb, f16* __restrict__ Ke) {
    long gid = (long)blockIdx.x * blockDim.x + threadIdx.x;  // 64*1024*8
    int d8 = (int)(gid & 7) * 8;
    int j = (int)((gid >> 3) & 1023);
    int h = (int)(gid >> 13);
    int n = h & 15;
    f16x8 kv;
    if (j < 1023) {
        const float* rp = &remb[((long)(j + 1) * 16 + n) * 64 + d8];
        float4 r0 = *(const float4*)rp, r1 = *(const float4*)(rp + 4);
        kv[0] = (f16)r0.x; kv[1] = (f16)r0.y; kv[2] = (f16)r0.z; kv[3] = (f16)r0.w;
        kv[4] = (f16)r1.x; kv[5] = (f16)r1.y; kv[6] = (f16)r1.z; kv[7] = (f16)r1.w;
    } else {
        kv = f16x8{};
    }
    *(f16x8*)&Ke[(((long)h << 10) + j) * 64 + d8] = kv;
}

// ---------------- NT GEMM, BK=64, global_load_lds staging, fused epilogues ----------------
// R6: BK=64 halves the per-K-step barrier-drain events (16 iters instead of 32
// at K=1024) with identical MFMA/ds_read volume; staging segments grow 64B->128B
// (better coalescing). LDS layout uses the flash-v10 both-sides XOR swizzle:
// linear gload_lds dest + source 16B-chunk ^ (row&7) + same XOR on frag reads
// -> frag reads stay conflict-free (8 accesses/bank-group, the optimum).
// Accumulation order is unchanged vs BK=32 -> bit-identical output.
// EPI: 0 = f16 row-major; 5 = QKV: seg0/1 natural row-major, seg2 vT scatter.
// XCD-chunked block swizzle (T1): grids are multiples of 8 (QKV 768, Wo 512).
template <int BM, int BN, int BK, int WROWS, int WCOLS, int EPI>
__global__ __launch_bounds__(256) void k_gemm_nt(
    const f16* __restrict__ A, const f16* __restrict__ Bt, void* __restrict__ Cv,
    f16* __restrict__ qtp, f16* __restrict__ ktp, f16* __restrict__ vtp,
    int lda, int ldb, int ldc, int K)
{
    static_assert(BK == 64, "geometry below assumes BK=64");
    constexpr int TM = BM / (WROWS * 16);
    constexpr int TN = BN / (WCOLS * 16);
    __shared__ __align__(16) f16 sA[BM * 64];
    __shared__ __align__(16) f16 sB[BN * 64];

    const int tid = threadIdx.x;
    const int lane = tid & 63, wave = tid >> 6;
    const int wm = wave / WCOLS, wn = wave % WCOLS;

    const int nwg = gridDim.x * gridDim.y;
    const int flat = blockIdx.y * gridDim.x + blockIdx.x;
    const int cpx = nwg >> 3;
    const int swz = (flat & 7) * cpx + (flat >> 3);
    const int bx = swz % gridDim.x, by = swz / gridDim.x;
    const int m0 = by * BM, n0 = bx * BN;

    f32x4 acc[TM][TN] = {};

    const int lrow = lane & 15;
    const int quad = lane >> 4;
    // staging: 1KB chunk = 8 rows x 64 f16 (128B rows); 8 lanes/row
    const int srow = lane >> 3;            // row within chunk (0..7)
    const int scol = ((lane & 7) ^ (srow & 7)) * 8;   // inverse-swizzled src chunk

    for (int k0 = 0; k0 < K; k0 += 64) {
        __syncthreads();
        constexpr int CHA = BM / 8;   // 1KB chunks per A tile
#pragma unroll
        for (int ch = 0; ch < CHA / 4; ++ch) {
            int cc = ch * 4 + wave;
            __builtin_amdgcn_global_load_lds(
                (const AS1 void*)(const void*)&A[(long)(m0 + cc * 8 + srow) * lda + k0 + scol],
                (AS3 void*)(void*)&sA[cc * 512], 16, 0, 0);
        }
        constexpr int CHB = BN / 8;
#pragma unroll
        for (int ch = 0; ch < CHB / 4; ++ch) {
            int cc = ch * 4 + wave;
            __builtin_amdgcn_global_load_lds(
                (const AS1 void*)(const void*)&Bt[(long)(n0 + cc * 8 + srow) * ldb + k0 + scol],
                (AS3 void*)(void*)&sB[cc * 512], 16, 0, 0);
        }
        __syncthreads();

        // two K=32 slices per staged 64-col tile; swizzled chunk = kc ^ (row&7)
#pragma unroll
        for (int kk = 0; kk < 2; ++kk) {
            const int kcb = kk * 4 + quad;   // global 16B-chunk index (0..7)
            f16x8 af[TM], bfr[TN];
#pragma unroll
            for (int mi = 0; mi < TM; ++mi) {
                int R = wm * TM * 16 + mi * 16 + lrow;
                af[mi] = *(const f16x8*)&sA[R * 64 + ((kcb ^ (lrow & 7)) * 8)];
            }
#pragma unroll
            for (int ni = 0; ni < TN; ++ni) {
                int R = wn * TN * 16 + ni * 16 + lrow;
                bfr[ni] = *(const f16x8*)&sB[R * 64 + ((kcb ^ (lrow & 7)) * 8)];
            }
#pragma unroll
            for (int mi = 0; mi < TM; ++mi)
#pragma unroll
                for (int ni = 0; ni < TN; ++ni)
                    acc[mi][ni] = __builtin_amdgcn_mfma_f32_16x16x32_f16(af[mi], bfr[ni], acc[mi][ni], 0, 0, 0);
        }
    }

    const int crow = (lane >> 4) * 4;
    const int ccol = lane & 15;
#pragma unroll
    for (int mi = 0; mi < TM; ++mi)
#pragma unroll
        for (int ni = 0; ni < TN; ++ni)
#pragma unroll
            for (int r = 0; r < 4; ++r) {
                int gm = m0 + wm * TM * 16 + mi * 16 + crow + r;
                int gn = n0 + wn * TN * 16 + ni * 16 + ccol;
                float val = acc[mi][ni][r];
                if constexpr (EPI == 0) {
                    ((f16*)Cv)[(long)gm * ldc + gn] = (f16)val;
                } else {
                    int seg = n0 >> 10;       // block-uniform (BN=128 | 1024)
                    int col = gn & 1023;
                    if (seg == 0) {
                        qtp[(long)gm * 1024 + col] = (f16)val;
                    } else if (seg == 1) {
                        ktp[(long)gm * 1024 + col] = (f16)val;
                    } else {
                        int b = gm >> 10, i = gm & 1023;
                        vtp[(((long)(b << 10) + col) << 10) + i] = (f16)val;
                    }
                }
            }
}

// ---------------- fused flash attention v11: async dbuf + log2-domain softmax.
// (unchanged from R5 — see that round's notes)
__global__ __launch_bounds__(512, 4) void k_flash(
    const f16* __restrict__ qh, const f16* __restrict__ kh,
    const f16* __restrict__ Ke, const f16* __restrict__ vT,
    const float* __restrict__ rwb, const float* __restrict__ r_bias,
    f16* __restrict__ avp)
{
    __shared__ __align__(16) f16 sKa[2][64 * 64];   // kh tile: [j-local][d]
    __shared__ __align__(16) f16 sKe[2][64 * 64];   // Ke tile: [j-local][d]
    __shared__ __align__(16) f16 sVa[2][64 * 64];   // vT tile: [d][j-local]
    __shared__ float sRB[2][64];

    const int tid = threadIdx.x, lane = tid & 63, wave = tid >> 6;  // wave 0..7
    const int bid = blockIdx.x;
    const int h = (((bid >> 3) & 7) << 3) | (bid & 7);
    const int i0 = (bid >> 6) * 128;
    const int b = h >> 4, n = h & 15;

    const int lrow = lane & 15;            // q (B-frag n) / row index
    const int quad = lane >> 4;
    const int lr3 = lane >> 3;             // staging: row within wave's 8-row slice
    const int swc = (lane & 7) ^ (lr3 & 7);  // inverse-swizzled source 16B chunk

    // wave-slice per-lane source pointers (tile row = 8*wave + lr3)
    const f16* srcK = kh + ((long)(b * Qc) + 8 * wave + lr3) * 1024 + n * 64 + swc * 8;
    const f16* srcE = Ke + ((long)h * Qc + 8 * wave + lr3) * 64 + swc * 8;
    const f16* srcV = vT + (long)h * DHc * Qc + (long)(8 * wave + lr3) * Qc + swc * 8;

    // r_w_bias fragments (f32 -> f16), pre-scaled by ATT_SCALE
    f16x8 rw0, rw1;
#pragma unroll
    for (int e = 0; e < 8; ++e) {
        rw0[e] = (f16)(rwb[n * 64 + quad * 8 + e] * ATT_SCALE);
        rw1[e] = (f16)(rwb[n * 64 + 32 + quad * 8 + e] * ATT_SCALE);
    }

    // Q fragments (B-operand of S^T): wave owns q rows [i0+wave*16, +16).
    const f16 qsc = (f16)0.125f;
    f16x8 aq[4];
    {
        long rix = (long)(b * Qc + i0 + wave * 16 + lrow) * 1024 + n * 64;
        f16x8 q0 = *(const f16x8*)&qh[rix + quad * 8] * qsc;
        f16x8 q1 = *(const f16x8*)&qh[rix + 32 + quad * 8] * qsc;
        aq[0] = q0 + rw0;   // k-dim [0,32):  (q + r_w_bias) * scale, dot kh
        aq[1] = q1 + rw1;   // k-dim [32,64)
        aq[2] = q0;         // k-dim [64,96):  q * scale, dot Ke
        aq[3] = q1;         // k-dim [96,128)
    }

    float m_i = -1e30f, l_i = 0.0f;   // m in log2 domain
    f32x4 o_acc[4] = {};   // D[m=q][n=d]: row q=quad*4+reg, col d=lane&15

    // prologue: stage tile 0 (async) + rb0
    {
        float rbv = 0.0f;
        if (tid < 64) rbv = r_bias[(tid + 1) * Nh + n] * (ATT_SCALE * LOG2E);
        __builtin_amdgcn_global_load_lds((const AS1 void*)srcK, (AS3 void*)&sKa[0][wave * 512], 16, 0, 0);
        __builtin_amdgcn_global_load_lds((const AS1 void*)srcE, (AS3 void*)&sKe[0][wave * 512], 16, 0, 0);
        __builtin_amdgcn_global_load_lds((const AS1 void*)srcV, (AS3 void*)&sVa[0][wave * 512], 16, 0, 0);
        if (tid < 64) sRB[0][tid] = rbv;
    }
    __syncthreads();   // drains vmcnt(0): tile 0 resident

    for (int jt = 0; jt < 16; ++jt) {
        const int cur = jt & 1;

        // issue next tile's async loads FIRST (in flight across compute below)
        float rbn = 0.0f;
        if (jt < 15) {
            const int j0n = (jt + 1) * 64;
            __builtin_amdgcn_global_load_lds((const AS1 void*)(srcK + (long)j0n * 1024),
                                             (AS3 void*)&sKa[cur ^ 1][wave * 512], 16, 0, 0);
            __builtin_amdgcn_global_load_lds((const AS1 void*)(srcE + (long)j0n * 64),
                                             (AS3 void*)&sKe[cur ^ 1][wave * 512], 16, 0, 0);
            __builtin_amdgcn_global_load_lds((const AS1 void*)(srcV + j0n),
                                             (AS3 void*)&sVa[cur ^ 1][wave * 512], 16, 0, 0);
            if (tid < 64) {
                int j = j0n + tid;
                rbn = (j < Qc - 1) ? r_bias[(j + 1) * Nh + n] * (ATT_SCALE * LOG2E) : 0.0f;
            }
        }

        const f16* Ka = &sKa[cur][0];
        const f16* Kb = &sKe[cur][0];
        const f16* Va = &sVa[cur][0];
        const int rsw = lrow & 7;

        // S^T: D[m=j][n=q], 64 j x 16 q per wave; K=128 (kh | Ke)
        f32x4 s_acc[4] = {};
#pragma unroll
        for (int ni = 0; ni < 4; ++ni) {
            int rb_ = (ni * 16 + lrow) * 64;
            f16x8 a0 = *(const f16x8*)&Ka[rb_ + ((0 + quad) ^ rsw) * 8];
            f16x8 a1 = *(const f16x8*)&Ka[rb_ + ((4 + quad) ^ rsw) * 8];
            f16x8 e0 = *(const f16x8*)&Kb[rb_ + ((0 + quad) ^ rsw) * 8];
            f16x8 e1 = *(const f16x8*)&Kb[rb_ + ((4 + quad) ^ rsw) * 8];
            s_acc[ni] = __builtin_amdgcn_mfma_f32_16x16x32_f16(a0, aq[0], s_acc[ni], 0, 0, 0);
            s_acc[ni] = __builtin_amdgcn_mfma_f32_16x16x32_f16(a1, aq[1], s_acc[ni], 0, 0, 0);
            s_acc[ni] = __builtin_amdgcn_mfma_f32_16x16x32_f16(e0, aq[2], s_acc[ni], 0, 0, 0);
            s_acc[ni] = __builtin_amdgcn_mfma_f32_16x16x32_f16(e1, aq[3], s_acc[ni], 0, 0, 0);
        }

        // online softmax per q (= lane&15), log2 domain; v = fma(s, log2e, rb)
        f16x4 pf[4];
        float mx = -1e30f;
#pragma unroll
        for (int ni = 0; ni < 4; ++ni) {
            f32x4 rb4 = *(const f32x4*)&sRB[cur][ni * 16 + quad * 4];
#pragma unroll
            for (int r = 0; r < 4; ++r) {
                float v = fmaf(s_acc[ni][r], LOG2E, rb4[r]);
                s_acc[ni][r] = v;
                mx = fmaxf(mx, v);
            }
        }
        mx = fmaxf(mx, __shfl_xor(mx, 16));
        mx = fmaxf(mx, __shfl_xor(mx, 32));
        float mn = fmaxf(m_i, mx);
        float alpha = __builtin_amdgcn_exp2f(m_i - mn);
        float sm = 0.0f;
#pragma unroll
        for (int ni = 0; ni < 4; ++ni) {
            float e0 = __builtin_amdgcn_exp2f(s_acc[ni][0] - mn);
            float e1 = __builtin_amdgcn_exp2f(s_acc[ni][1] - mn);
            float e2 = __builtin_amdgcn_exp2f(s_acc[ni][2] - mn);
            float e3 = __builtin_amdgcn_exp2f(s_acc[ni][3] - mn);
            sm += (e0 + e1) + (e2 + e3);
            f16x4 pvv; pvv[0] = (f16)e0; pvv[1] = (f16)e1; pvv[2] = (f16)e2; pvv[3] = (f16)e3;
            pf[ni] = pvv;
        }
        sm += __shfl_xor(sm, 16);
        sm += __shfl_xor(sm, 32);
        l_i = l_i * alpha + sm;
        m_i = mn;

        // rescale o_acc: broadcast alpha from lane (quad*4+r) of the q-group
#pragma unroll
        for (int r = 0; r < 4; ++r) {
            float al = __shfl(alpha, quad * 4 + r);
#pragma unroll
            for (int dt = 0; dt < 4; ++dt) o_acc[dt][r] *= al;
        }

        // PV: D[m=q][n=d] += P[q][j] * V[j][d], K=16 chunks, P from registers.
        // sVa read with source-matched swizzle (16B chunk ^ (d&7)).
#pragma unroll
        for (int nj = 0; nj < 4; ++nj) {
            int coff = ((2 * nj + (quad >> 1)) ^ rsw) * 8 + (quad & 1) * 4;
#pragma unroll
            for (int dt = 0; dt < 4; ++dt) {
                f16x4 bv = *(const f16x4*)&Va[(dt * 16 + lrow) * 64 + coff];
                o_acc[dt] = __builtin_amdgcn_mfma_f32_16x16x16f16(pf[nj], bv, o_acc[dt], 0, 0, 0);
            }
        }

        if (jt < 15) {
            if (tid < 64) sRB[cur ^ 1][tid] = rbn;
            __syncthreads();   // drains vmcnt: next tile resident; rb visible
        }
    }

    // epilogue: avp[b][i][n*64+d] = O / l  (row q=quad*4+r, col d=lane&15)
    {
        float linv = 1.0f / l_i;
#pragma unroll
        for (int r = 0; r < 4; ++r) {
            float li = __shfl(linv, quad * 4 + r);
            int i = i0 + wave * 16 + quad * 4 + r;
#pragma unroll
            for (int dt = 0; dt < 4; ++dt) {
                int d = dt * 16 + lrow;
                avp[((long)(b * Qc + i) << 10) + n * 64 + d] = (f16)(o_acc[dt][r] * li);
            }
        }
    }
}

// ---------------- residual + LayerNorm (w f32, ao f16; f32 output) ----------------
__global__ __launch_bounds__(256) void k_res_ln(const float* __restrict__ w, const f16* __restrict__ ao,
                                                const float* __restrict__ gamma, const float* __restrict__ beta,
                                                float* __restrict__ out) {
    const long base = (long)blockIdx.x * 1024;
    const int tid = threadIdx.x;
    float4 wv = *(const float4*)&w[base + tid * 4];
    f16x4 av = *(const f16x4*)&ao[base + tid * 4];
    float x[4] = { wv.x + (float)av[0], wv.y + (float)av[1],
                   wv.z + (float)av[2], wv.w + (float)av[3] };
    float s = x[0] + x[1] + x[2] + x[3];
    float s2 = x[0] * x[0] + x[1] * x[1] + x[2] * x[2] + x[3] * x[3];
#pragma unroll
    for (int off = 32; off; off >>= 1) { s += __shfl_down(s, off); s2 += __shfl_down(s2, off); }
    __shared__ float rs[4], rs2[4];
    if ((tid & 63) == 0) { rs[tid >> 6] = s; rs2[tid >> 6] = s2; }
    __syncthreads();
    s = rs[0] + rs[1] + rs[2] + rs[3];
    s2 = rs2[0] + rs2[1] + rs2[2] + rs2[3];
    float mu = s * (1.0f / 1024.0f);
    float var = s2 * (1.0f / 1024.0f) - mu * mu;
    float inv = rsqrtf(var + 1e-5f);
    float4 gv = *(const float4*)&gamma[tid * 4];
    float4 bv = *(const float4*)&beta[tid * 4];
    float4 o;
    o.x = (x[0] - mu) * inv * gv.x + bv.x;
    o.y = (x[1] - mu) * inv * gv.y + bv.y;
    o.z = (x[2] - mu) * inv * gv.z + bv.z;
    o.w = (x[3] - mu) * inv * gv.w + bv.w;
    *(float4*)&out[base + tid * 4] = o;
}

extern "C" void kernel_launch(void* const* d_in, const int* in_sizes, int n_in,
                              void* d_out, int out_size, void* d_ws, size_t ws_size,
                              hipStream_t stream) {
    const float* w_in   = (const float*)d_in[0];
    const float* r_emb  = (const float*)d_in[1];
    const float* r_wb   = (const float*)d_in[2];
    const float* r_bias = (const float*)d_in[3];
    const float* Wq     = (const float*)d_in[4];
    const float* Wk     = (const float*)d_in[5];
    const float* Wv     = (const float*)d_in[6];
    const float* Wo     = (const float*)d_in[7];
    const float* ln_g   = (const float*)d_in[8];
    const float* ln_b   = (const float*)d_in[9];
    float* out = (float*)d_out;

    // workspace carve-out (48MB fixed + aliases)
    char* p = (char*)d_ws;
    auto alloc = [&](size_t bytes) { char* r = p; p += (bytes + 255) & ~(size_t)255; return r; };
    f16* wh = (f16*)alloc((size_t)BQ * Dc * 2);          // 8 MB
    f16* WT = (f16*)alloc((size_t)4 * Dc * Dc * 2);      // 8 MB: WqT,WkT,WvT,WoT (contiguous)
    f16* qh = (f16*)alloc((size_t)BQ * Dc * 2);          // 8 MB [b*Q+i][n*64+d]
    f16* kh = (f16*)alloc((size_t)BQ * Dc * 2);          // 8 MB [b*Q+j][n*64+d]
    f16* Ke = (f16*)alloc((size_t)NHEAD * Qc * DHc * 2); // 8 MB [h][j][64] rel-shifted r_emb
    f16* vT = (f16*)alloc((size_t)BQ * Dc * 2);          // 8 MB [b][dcol][j]
    f16* WoT = WT + (size_t)3 * Dc * Dc;
    // aliases (liveness-checked): wh dead after QKV GEMM; Ke dead after flash
    f16* avp = wh;                 // [b][i][1024] f16
    f16* ao  = Ke;                 // 8 MB f16

    // 1. f32->f16 of w (8/thread)
    k_f2h<<<(BQ * Dc) / (256 * 8), 256, 0, stream>>>(w_in, wh);

    // 2. transpose 4 weights in one dispatch (f32 -> f16)
    Ptr4 srcs{{Wq, Wk, Wv, Wo}};
    k_transpose4<<<dim3(32, 32, 4), dim3(32, 8), 0, stream>>>(srcs, WT);

    // 3. rel-shifted r_emb -> Ke (independent of GEMMs)
    k_fill_remb<<<(NHEAD * Qc * 8) / 256, 256, 0, stream>>>(r_emb, Ke);

    // 4. fused QKV projection: N=3072; seg0/1 natural row-major, seg2 vT scatter
    k_gemm_nt<128, 128, 64, 2, 2, 5><<<dim3(3 * Dc / 128, BQ / 128), 256, 0, stream>>>(
        wh, WT, nullptr, qh, kh, vT, Dc, Dc, 0, Dc);

    // 5. fused attention (XCD-swizzled 1D grid 512, 8-wave blocks, async dbuf)
    k_flash<<<512, 512, 0, stream>>>(qh, kh, Ke, vT, r_wb, r_bias, avp);

    // 6. attn_out = avp @ Wo^T (64x128 tile -> 512 blocks; f16 out into aliased ao)
    k_gemm_nt<64, 128, 64, 2, 2, 0><<<dim3(Dc / 128, BQ / 64), 256, 0, stream>>>(
        avp, WoT, ao, nullptr, nullptr, nullptr, Dc, Dc, Dc, Dc);

    // 7. out = LayerNorm(w + attn_out), fp32 output
    k_res_ln<<<BQ, 256, 0, stream>>>(w_in, ao, ln_g, ln_b, out);
}

// Round 8
// 199.678 us; speedup vs baseline: 1.0993x; 1.0186x over previous
//
#include <hip/hip_runtime.h>
#include <hip/hip_bf16.h>

using f16 = _Float16;
typedef _Float16 f16x8 __attribute__((ext_vector_type(8)));
typedef _Float16 f16x4 __attribute__((ext_vector_type(4)));
typedef float f32x4 __attribute__((ext_vector_type(4)));

#define AS1 __attribute__((address_space(1)))
#define AS3 __attribute__((address_space(3)))

// Problem constants
constexpr int Bc = 4, Qc = 1024, Dc = 1024, Nh = 16, DHc = 64;
constexpr int BQ = Bc * Qc;      // 4096 rows of w
constexpr int NHEAD = Bc * Nh;   // 64 (b,n) heads
constexpr float ATT_SCALE = 0.125f;
constexpr float LOG2E = 1.44269504088896f;

// ---------------- merged preprocessing: f2h | 4-way transpose | rel-shift r_emb ----------------
// One dispatch instead of three: blocks [0,2048) = f2h of w,
// [2048,6144) = weight transpose (f32->f16), [6144,8192) = Ke fill.
struct Ptr4 { const float* p[4]; };
__global__ __launch_bounds__(256) void k_prep(
    const float* __restrict__ w_in, f16* __restrict__ wh,
    Ptr4 srcs, f16* __restrict__ WT,
    const float* __restrict__ remb, f16* __restrict__ Ke)
{
    const int bid = blockIdx.x, tid = threadIdx.x;
    if (bid < 2048) {
        long i8 = ((long)bid * 256 + tid) * 8;
        float4 a = *(const float4*)&w_in[i8];
        float4 b = *(const float4*)&w_in[i8 + 4];
        f16x8 o = { (f16)a.x, (f16)a.y, (f16)a.z, (f16)a.w,
                    (f16)b.x, (f16)b.y, (f16)b.z, (f16)b.w };
        *(f16x8*)&wh[i8] = o;
    } else if (bid < 6144) {
        __shared__ f16 tile[32][33];
        int idx = bid - 2048;
        int z = idx >> 10, rem = idx & 1023;
        int r0 = (rem >> 5) * 32, c0 = (rem & 31) * 32;
        const float* src = srcs.p[z];
        f16* d = WT + (long)z * Dc * Dc;
        int tx = tid & 31, ty = tid >> 5;   // 32 x 8
#pragma unroll
        for (int dy = 0; dy < 32; dy += 8) {
            int r = r0 + ty + dy, c = c0 + tx;
            tile[ty + dy][tx] = (f16)src[(long)r * Dc + c];
        }
        __syncthreads();
#pragma unroll
        for (int dy = 0; dy < 32; dy += 8) {
            int c = c0 + ty + dy, r = r0 + tx;
            d[(long)c * Dc + r] = tile[tx][ty + dy];
        }
    } else {
        long gid = (long)(bid - 6144) * 256 + tid;  // 64*1024*8
        int d8 = (int)(gid & 7) * 8;
        int j = (int)((gid >> 3) & 1023);
        int h = (int)(gid >> 13);
        int n = h & 15;
        f16x8 kv;
        if (j < 1023) {
            const float* rp = &remb[((long)(j + 1) * 16 + n) * 64 + d8];
            float4 r0 = *(const float4*)rp, r1 = *(const float4*)(rp + 4);
            kv[0] = (f16)r0.x; kv[1] = (f16)r0.y; kv[2] = (f16)r0.z; kv[3] = (f16)r0.w;
            kv[4] = (f16)r1.x; kv[5] = (f16)r1.y; kv[6] = (f16)r1.z; kv[7] = (f16)r1.w;
        } else {
            kv = f16x8{};
        }
        *(f16x8*)&Ke[(((long)h << 10) + j) * 64 + d8] = kv;
    }
}

// ---------------- NT GEMM, BK=64, global_load_lds staging, fused epilogues ----------------
// (unchanged from R6: both-sides XOR swizzle, XCD-chunked block swizzle, BK=64)
template <int BM, int BN, int BK, int WROWS, int WCOLS, int EPI>
__global__ __launch_bounds__(256) void k_gemm_nt(
    const f16* __restrict__ A, const f16* __restrict__ Bt, void* __restrict__ Cv,
    f16* __restrict__ qtp, f16* __restrict__ ktp, f16* __restrict__ vtp,
    int lda, int ldb, int ldc, int K)
{
    static_assert(BK == 64, "geometry below assumes BK=64");
    constexpr int TM = BM / (WROWS * 16);
    constexpr int TN = BN / (WCOLS * 16);
    __shared__ __align__(16) f16 sA[BM * 64];
    __shared__ __align__(16) f16 sB[BN * 64];

    const int tid = threadIdx.x;
    const int lane = tid & 63, wave = tid >> 6;
    const int wm = wave / WCOLS, wn = wave % WCOLS;

    const int nwg = gridDim.x * gridDim.y;
    const int flat = blockIdx.y * gridDim.x + blockIdx.x;
    const int cpx = nwg >> 3;
    const int swz = (flat & 7) * cpx + (flat >> 3);
    const int bx = swz % gridDim.x, by = swz / gridDim.x;
    const int m0 = by * BM, n0 = bx * BN;

    f32x4 acc[TM][TN] = {};

    const int lrow = lane & 15;
    const int quad = lane >> 4;
    const int srow = lane >> 3;            // row within 1KB chunk (0..7)
    const int scol = ((lane & 7) ^ (srow & 7)) * 8;   // inverse-swizzled src chunk

    for (int k0 = 0; k0 < K; k0 += 64) {
        __syncthreads();
        constexpr int CHA = BM / 8;   // 1KB chunks per A tile
#pragma unroll
        for (int ch = 0; ch < CHA / 4; ++ch) {
            int cc = ch * 4 + wave;
            __builtin_amdgcn_global_load_lds(
                (const AS1 void*)(const void*)&A[(long)(m0 + cc * 8 + srow) * lda + k0 + scol],
                (AS3 void*)(void*)&sA[cc * 512], 16, 0, 0);
        }
        constexpr int CHB = BN / 8;
#pragma unroll
        for (int ch = 0; ch < CHB / 4; ++ch) {
            int cc = ch * 4 + wave;
            __builtin_amdgcn_global_load_lds(
                (const AS1 void*)(const void*)&Bt[(long)(n0 + cc * 8 + srow) * ldb + k0 + scol],
                (AS3 void*)(void*)&sB[cc * 512], 16, 0, 0);
        }
        __syncthreads();

        // two K=32 slices per staged 64-col tile; swizzled chunk = kc ^ (row&7)
#pragma unroll
        for (int kk = 0; kk < 2; ++kk) {
            const int kcb = kk * 4 + quad;   // global 16B-chunk index (0..7)
            f16x8 af[TM], bfr[TN];
#pragma unroll
            for (int mi = 0; mi < TM; ++mi) {
                int R = wm * TM * 16 + mi * 16 + lrow;
                af[mi] = *(const f16x8*)&sA[R * 64 + ((kcb ^ (lrow & 7)) * 8)];
            }
#pragma unroll
            for (int ni = 0; ni < TN; ++ni) {
                int R = wn * TN * 16 + ni * 16 + lrow;
                bfr[ni] = *(const f16x8*)&sB[R * 64 + ((kcb ^ (lrow & 7)) * 8)];
            }
#pragma unroll
            for (int mi = 0; mi < TM; ++mi)
#pragma unroll
                for (int ni = 0; ni < TN; ++ni)
                    acc[mi][ni] = __builtin_amdgcn_mfma_f32_16x16x32_f16(af[mi], bfr[ni], acc[mi][ni], 0, 0, 0);
        }
    }

    const int crow = (lane >> 4) * 4;
    const int ccol = lane & 15;
#pragma unroll
    for (int mi = 0; mi < TM; ++mi)
#pragma unroll
        for (int ni = 0; ni < TN; ++ni)
#pragma unroll
            for (int r = 0; r < 4; ++r) {
                int gm = m0 + wm * TM * 16 + mi * 16 + crow + r;
                int gn = n0 + wn * TN * 16 + ni * 16 + ccol;
                float val = acc[mi][ni][r];
                if constexpr (EPI == 0) {
                    ((f16*)Cv)[(long)gm * ldc + gn] = (f16)val;
                } else {
                    int seg = n0 >> 10;       // block-uniform (BN=128 | 1024)
                    int col = gn & 1023;
                    if (seg == 0) {
                        qtp[(long)gm * 1024 + col] = (f16)val;
                    } else if (seg == 1) {
                        ktp[(long)gm * 1024 + col] = (f16)val;
                    } else {
                        int b = gm >> 10, i = gm & 1023;
                        vtp[(((long)(b << 10) + col) << 10) + i] = (f16)val;
                    }
                }
            }
}

// ---------------- fused flash attention v13: v12's defer-max FIXED.
// R7 NaN root cause: dropping the per-iter cross-lane l-reduction made l_i a
// per-lane partial; lanes whose 16 j-values underflow exp2 accumulated l_i=0
// -> 1/l_i = inf -> 0*inf = NaN in the epilogue (and the denominator was wrong
// anyway). Fix: m_i/alpha are ALWAYS q-group-uniform (init uniform; updated
// only from wave-reduced wmx), so per-lane l partials stay in one consistent
// scaling and the cross-lane sum can be DEFERRED TO THE EPILOGUE: two
// shfl_xor once per kernel, zero cross-lane ops in the common path.
// l_total > 0 guaranteed: the tile that set m contributes >= 2^-8.
// Tripwires: WRITE_SIZE == 8192 KB, VGPR <= 72; FETCH ~16.7MB; absmax must be
// <= 0.108 threshold, expect ~0.03-0.06; revert defer if above.
__global__ __launch_bounds__(512, 4) void k_flash(
    const f16* __restrict__ qh, const f16* __restrict__ kh,
    const f16* __restrict__ Ke, const f16* __restrict__ vT,
    const float* __restrict__ rwb, const float* __restrict__ r_bias,
    f16* __restrict__ avp)
{
    __shared__ __align__(16) f16 sKa[2][64 * 64];   // kh tile: [j-local][d]
    __shared__ __align__(16) f16 sKe[2][64 * 64];   // Ke tile: [j-local][d]
    __shared__ __align__(16) f16 sVa[2][64 * 64];   // vT tile: [d][j-local]
    __shared__ float sRB[2][64];

    const int tid = threadIdx.x, lane = tid & 63, wave = tid >> 6;  // wave 0..7
    const int bid = blockIdx.x;
    const int h = (((bid >> 3) & 7) << 3) | (bid & 7);
    const int i0 = (bid >> 6) * 128;
    const int b = h >> 4, n = h & 15;

    const int lrow = lane & 15;            // q (B-frag n) / row index
    const int quad = lane >> 4;
    const int lr3 = lane >> 3;             // staging: row within wave's 8-row slice
    const int swc = (lane & 7) ^ (lr3 & 7);  // inverse-swizzled source 16B chunk

    // wave-slice per-lane source pointers (tile row = 8*wave + lr3)
    const f16* srcK = kh + ((long)(b * Qc) + 8 * wave + lr3) * 1024 + n * 64 + swc * 8;
    const f16* srcE = Ke + ((long)h * Qc + 8 * wave + lr3) * 64 + swc * 8;
    const f16* srcV = vT + (long)h * DHc * Qc + (long)(8 * wave + lr3) * Qc + swc * 8;

    // r_w_bias fragments (f32 -> f16), pre-scaled by ATT_SCALE
    f16x8 rw0, rw1;
#pragma unroll
    for (int e = 0; e < 8; ++e) {
        rw0[e] = (f16)(rwb[n * 64 + quad * 8 + e] * ATT_SCALE);
        rw1[e] = (f16)(rwb[n * 64 + 32 + quad * 8 + e] * ATT_SCALE);
    }

    // Q fragments (B-operand of S^T): wave owns q rows [i0+wave*16, +16).
    const f16 qsc = (f16)0.125f;
    f16x8 aq[4];
    {
        long rix = (long)(b * Qc + i0 + wave * 16 + lrow) * 1024 + n * 64;
        f16x8 q0 = *(const f16x8*)&qh[rix + quad * 8] * qsc;
        f16x8 q1 = *(const f16x8*)&qh[rix + 32 + quad * 8] * qsc;
        aq[0] = q0 + rw0;   // k-dim [0,32):  (q + r_w_bias) * scale, dot kh
        aq[1] = q1 + rw1;   // k-dim [32,64)
        aq[2] = q0;         // k-dim [64,96):  q * scale, dot Ke
        aq[3] = q1;         // k-dim [96,128)
    }

    float m_i = -1e30f, l_i = 0.0f;   // m: log2 domain, q-group uniform; l: per-lane partial
    f32x4 o_acc[4] = {};   // D[m=q][n=d]: row q=quad*4+reg, col d=lane&15

    // prologue: stage tile 0 (async) + rb0
    {
        float rbv = 0.0f;
        if (tid < 64) rbv = r_bias[(tid + 1) * Nh + n] * (ATT_SCALE * LOG2E);
        __builtin_amdgcn_global_load_lds((const AS1 void*)srcK, (AS3 void*)&sKa[0][wave * 512], 16, 0, 0);
        __builtin_amdgcn_global_load_lds((const AS1 void*)srcE, (AS3 void*)&sKe[0][wave * 512], 16, 0, 0);
        __builtin_amdgcn_global_load_lds((const AS1 void*)srcV, (AS3 void*)&sVa[0][wave * 512], 16, 0, 0);
        if (tid < 64) sRB[0][tid] = rbv;
    }
    __syncthreads();   // drains vmcnt(0): tile 0 resident

    for (int jt = 0; jt < 16; ++jt) {
        const int cur = jt & 1;

        // issue next tile's async loads FIRST (in flight across compute below)
        float rbn = 0.0f;
        if (jt < 15) {
            const int j0n = (jt + 1) * 64;
            __builtin_amdgcn_global_load_lds((const AS1 void*)(srcK + (long)j0n * 1024),
                                             (AS3 void*)&sKa[cur ^ 1][wave * 512], 16, 0, 0);
            __builtin_amdgcn_global_load_lds((const AS1 void*)(srcE + (long)j0n * 64),
                                             (AS3 void*)&sKe[cur ^ 1][wave * 512], 16, 0, 0);
            __builtin_amdgcn_global_load_lds((const AS1 void*)(srcV + j0n),
                                             (AS3 void*)&sVa[cur ^ 1][wave * 512], 16, 0, 0);
            if (tid < 64) {
                int j = j0n + tid;
                rbn = (j < Qc - 1) ? r_bias[(j + 1) * Nh + n] * (ATT_SCALE * LOG2E) : 0.0f;
            }
        }

        const f16* Ka = &sKa[cur][0];
        const f16* Kb = &sKe[cur][0];
        const f16* Va = &sVa[cur][0];
        const int rsw = lrow & 7;

        // S^T: D[m=j][n=q], 64 j x 16 q per wave; K=128 (kh | Ke)
        f32x4 s_acc[4] = {};
#pragma unroll
        for (int ni = 0; ni < 4; ++ni) {
            int rb_ = (ni * 16 + lrow) * 64;
            f16x8 a0 = *(const f16x8*)&Ka[rb_ + ((0 + quad) ^ rsw) * 8];
            f16x8 a1 = *(const f16x8*)&Ka[rb_ + ((4 + quad) ^ rsw) * 8];
            f16x8 e0 = *(const f16x8*)&Kb[rb_ + ((0 + quad) ^ rsw) * 8];
            f16x8 e1 = *(const f16x8*)&Kb[rb_ + ((4 + quad) ^ rsw) * 8];
            s_acc[ni] = __builtin_amdgcn_mfma_f32_16x16x32_f16(a0, aq[0], s_acc[ni], 0, 0, 0);
            s_acc[ni] = __builtin_amdgcn_mfma_f32_16x16x32_f16(a1, aq[1], s_acc[ni], 0, 0, 0);
            s_acc[ni] = __builtin_amdgcn_mfma_f32_16x16x32_f16(e0, aq[2], s_acc[ni], 0, 0, 0);
            s_acc[ni] = __builtin_amdgcn_mfma_f32_16x16x32_f16(e1, aq[3], s_acc[ni], 0, 0, 0);
        }

        // speculative online softmax (log2 domain): P = exp2(v - m_old) fused
        // with the max scan; rescale path only when the wave-uniform test fires.
        f16x4 pf[4];
        float mx = -1e30f, sm = 0.0f;
#pragma unroll
        for (int ni = 0; ni < 4; ++ni) {
            f32x4 rb4 = *(const f32x4*)&sRB[cur][ni * 16 + quad * 4];
            f16x4 pvv;
#pragma unroll
            for (int r = 0; r < 4; ++r) {
                float v = fmaf(s_acc[ni][r], LOG2E, rb4[r]);
                s_acc[ni][r] = v;
                mx = fmaxf(mx, v);
                float e = __builtin_amdgcn_exp2f(v - m_i);
                sm += e;
                pvv[r] = (f16)e;
            }
            pf[ni] = pvv;
        }
        if (!__all(mx - m_i <= 8.0f)) {
            float wmx = fmaxf(mx, __shfl_xor(mx, 16));
            wmx = fmaxf(wmx, __shfl_xor(wmx, 32));
            float mn = fmaxf(m_i, wmx);            // q-group uniform
            float alpha = __builtin_amdgcn_exp2f(m_i - mn);   // q-group uniform
            sm = 0.0f;
#pragma unroll
            for (int ni = 0; ni < 4; ++ni) {
                f16x4 pvv;
#pragma unroll
                for (int r = 0; r < 4; ++r) {
                    float e = __builtin_amdgcn_exp2f(s_acc[ni][r] - mn);
                    sm += e;
                    pvv[r] = (f16)e;
                }
                pf[ni] = pvv;
            }
            l_i *= alpha;   // uniform scaling keeps per-lane partials consistent
#pragma unroll
            for (int r = 0; r < 4; ++r) {
                float al = __shfl(alpha, quad * 4 + r);
#pragma unroll
                for (int dt = 0; dt < 4; ++dt) o_acc[dt][r] *= al;
            }
            m_i = mn;
        }
        l_i += sm;

        // PV: D[m=q][n=d] += P[q][j] * V[j][d], K=16 chunks, P from registers.
        // sVa read with source-matched swizzle (16B chunk ^ (d&7)).
#pragma unroll
        for (int nj = 0; nj < 4; ++nj) {
            int coff = ((2 * nj + (quad >> 1)) ^ rsw) * 8 + (quad & 1) * 4;
#pragma unroll
            for (int dt = 0; dt < 4; ++dt) {
                f16x4 bv = *(const f16x4*)&Va[(dt * 16 + lrow) * 64 + coff];
                o_acc[dt] = __builtin_amdgcn_mfma_f32_16x16x16f16(pf[nj], bv, o_acc[dt], 0, 0, 0);
            }
        }

        if (jt < 15) {
            if (tid < 64) sRB[cur ^ 1][tid] = rbn;
            __syncthreads();   // drains vmcnt: next tile resident; rb visible
        }
    }

    // epilogue: deferred cross-lane l reduction (valid: all partials share the
    // same q-group-uniform m scaling), then avp = O / l.
    l_i += __shfl_xor(l_i, 16);
    l_i += __shfl_xor(l_i, 32);
    {
        float linv = 1.0f / l_i;
#pragma unroll
        for (int r = 0; r < 4; ++r) {
            float li = __shfl(linv, quad * 4 + r);
            int i = i0 + wave * 16 + quad * 4 + r;
#pragma unroll
            for (int dt = 0; dt < 4; ++dt) {
                int d = dt * 16 + lrow;
                avp[((long)(b * Qc + i) << 10) + n * 64 + d] = (f16)(o_acc[dt][r] * li);
            }
        }
    }
}

// ---------------- residual + LayerNorm (w f32, ao f16; f32 output) ----------------
__global__ __launch_bounds__(256) void k_res_ln(const float* __restrict__ w, const f16* __restrict__ ao,
                                                const float* __restrict__ gamma, const float* __restrict__ beta,
                                                float* __restrict__ out) {
    const long base = (long)blockIdx.x * 1024;
    const int tid = threadIdx.x;
    float4 wv = *(const float4*)&w[base + tid * 4];
    f16x4 av = *(const f16x4*)&ao[base + tid * 4];
    float x[4] = { wv.x + (float)av[0], wv.y + (float)av[1],
                   wv.z + (float)av[2], wv.w + (float)av[3] };
    float s = x[0] + x[1] + x[2] + x[3];
    float s2 = x[0] * x[0] + x[1] * x[1] + x[2] * x[2] + x[3] * x[3];
#pragma unroll
    for (int off = 32; off; off >>= 1) { s += __shfl_down(s, off); s2 += __shfl_down(s2, off); }
    __shared__ float rs[4], rs2[4];
    if ((tid & 63) == 0) { rs[tid >> 6] = s; rs2[tid >> 6] = s2; }
    __syncthreads();
    s = rs[0] + rs[1] + rs[2] + rs[3];
    s2 = rs2[0] + rs2[1] + rs2[2] + rs2[3];
    float mu = s * (1.0f / 1024.0f);
    float var = s2 * (1.0f / 1024.0f) - mu * mu;
    float inv = rsqrtf(var + 1e-5f);
    float4 gv = *(const float4*)&gamma[tid * 4];
    float4 bv = *(const float4*)&beta[tid * 4];
    float4 o;
    o.x = (x[0] - mu) * inv * gv.x + bv.x;
    o.y = (x[1] - mu) * inv * gv.y + bv.y;
    o.z = (x[2] - mu) * inv * gv.z + bv.z;
    o.w = (x[3] - mu) * inv * gv.w + bv.w;
    *(float4*)&out[base + tid * 4] = o;
}

extern "C" void kernel_launch(void* const* d_in, const int* in_sizes, int n_in,
                              void* d_out, int out_size, void* d_ws, size_t ws_size,
                              hipStream_t stream) {
    const float* w_in   = (const float*)d_in[0];
    const float* r_emb  = (const float*)d_in[1];
    const float* r_wb   = (const float*)d_in[2];
    const float* r_bias = (const float*)d_in[3];
    const float* Wq     = (const float*)d_in[4];
    const float* Wk     = (const float*)d_in[5];
    const float* Wv     = (const float*)d_in[6];
    const float* Wo     = (const float*)d_in[7];
    const float* ln_g   = (const float*)d_in[8];
    const float* ln_b   = (const float*)d_in[9];
    float* out = (float*)d_out;

    // workspace carve-out (48MB fixed + aliases)
    char* p = (char*)d_ws;
    auto alloc = [&](size_t bytes) { char* r = p; p += (bytes + 255) & ~(size_t)255; return r; };
    f16* wh = (f16*)alloc((size_t)BQ * Dc * 2);          // 8 MB
    f16* WT = (f16*)alloc((size_t)4 * Dc * Dc * 2);      // 8 MB: WqT,WkT,WvT,WoT (contiguous)
    f16* qh = (f16*)alloc((size_t)BQ * Dc * 2);          // 8 MB [b*Q+i][n*64+d]
    f16* kh = (f16*)alloc((size_t)BQ * Dc * 2);          // 8 MB [b*Q+j][n*64+d]
    f16* Ke = (f16*)alloc((size_t)NHEAD * Qc * DHc * 2); // 8 MB [h][j][64] rel-shifted r_emb
    f16* vT = (f16*)alloc((size_t)BQ * Dc * 2);          // 8 MB [b][dcol][j]
    f16* WoT = WT + (size_t)3 * Dc * Dc;
    // aliases (liveness-checked): wh dead after QKV GEMM; Ke dead after flash
    f16* avp = wh;                 // [b][i][1024] f16
    f16* ao  = Ke;                 // 8 MB f16

    // 1. merged preprocessing: f2h + weight transpose + Ke fill (one dispatch)
    Ptr4 srcs{{Wq, Wk, Wv, Wo}};
    k_prep<<<8192, 256, 0, stream>>>(w_in, wh, srcs, WT, r_emb, Ke);

    // 2. fused QKV projection: N=3072; seg0/1 natural row-major, seg2 vT scatter
    k_gemm_nt<128, 128, 64, 2, 2, 5><<<dim3(3 * Dc / 128, BQ / 128), 256, 0, stream>>>(
        wh, WT, nullptr, qh, kh, vT, Dc, Dc, 0, Dc);

    // 3. fused attention (XCD-swizzled 1D grid 512, 8-wave blocks, async dbuf)
    k_flash<<<512, 512, 0, stream>>>(qh, kh, Ke, vT, r_wb, r_bias, avp);

    // 4. attn_out = avp @ Wo^T (64x128 tile -> 512 blocks; f16 out into aliased ao)
    k_gemm_nt<64, 128, 64, 2, 2, 0><<<dim3(Dc / 128, BQ / 64), 256, 0, stream>>>(
        avp, WoT, ao, nullptr, nullptr, nullptr, Dc, Dc, Dc, Dc);

    // 5. out = LayerNorm(w + attn_out), fp32 output
    k_res_ln<<<BQ, 256, 0, stream>>>(w_in, ao, ln_g, ln_b, out);
}